// Round 1
// 563.886 us; speedup vs baseline: 1.0826x; 1.0826x over previous
//
#include <hip/hip_runtime.h>

#define NU 100000
#define NI 100000
#define NE 1600000
#define BB 16384
#define DD 128

static constexpr int SCAN_CHUNK = 2048;                       // 256 threads * 8
static constexpr int SCAN_NBLK  = (NU + SCAN_CHUNK - 1) / SCAN_CHUNK; // 49
static constexpr int USER_TILES = NU / 16;                    // 6250

static constexpr int NXCD   = 8;
static constexpr int DRANGE = NU / NXCD;                      // 12500 dsts per XCD range
static constexpr int PART_K = 128;                            // sub-blocks per range

// ---------- workspace layout (bytes) ----------
static constexpr size_t OFF_DEG      = 0;          // int[NU]   400000
static constexpr size_t OFF_ROWSTART = 400128;     // int[NU]
static constexpr size_t OFF_CURSOR   = 800256;     // int[NU]
static constexpr size_t OFF_BSUM     = 1200384;    // int[64]
static constexpr size_t OFF_EDGESRC  = 1200640;    // int[NE]   6400000
static constexpr size_t OFF_H1       = 7600640;    // float[NU*DD] 51200000
static constexpr size_t OFF_WFRAG    = 58800640;   // u32x4[12288] 196608 (pre-swizzled bf16 weights)
// end = 58,997,248 bytes

// d_out staging (dead before real outputs are written):
//   ubf   at d_out+0        : uint[NU*64]  25.6 MB  (ufeat in bf16 pairs)
//   hn_bf at d_out+25.6MB   : ushort[NU*128] 25.6 MB (neighbor mean, bf16)
// user_l2 writes rows 0..BB-1 (bytes 0..25.2M, ubf dead by then);
// item writes rows BB..3BB-1 (overlaps hn_bf region, dead by then).

typedef __bf16 bf16x8 __attribute__((ext_vector_type(8)));
typedef float f32x4 __attribute__((ext_vector_type(4)));
typedef unsigned int u32x4 __attribute__((ext_vector_type(4)));

union frag_u {
    u32x4 u;
    bf16x8 b;
    unsigned short us[8];
};

// ---------- helpers ----------
__device__ __forceinline__ unsigned short f2bf(float f) {
    unsigned u = __float_as_uint(f);
    u = (u + 0x7fffu + ((u >> 16) & 1u)) >> 16;  // RNE
    return (unsigned short)u;
}

__device__ __forceinline__ unsigned pack_bf16_pair(float a, float b) {
    return (unsigned)f2bf(a) | ((unsigned)f2bf(b) << 16);
}

__device__ __forceinline__ float2 unpack_bf16_pair(unsigned u) {
    float2 r;
    r.x = __uint_as_float(u << 16);
    r.y = __uint_as_float(u & 0xffff0000u);
    return r;
}

__device__ __forceinline__ f32x4 mfma16(bf16x8 a, bf16x8 b, f32x4 c) {
    return __builtin_amdgcn_mfma_f32_16x16x32_bf16(a, b, c, 0, 0, 0);
}

__device__ __forceinline__ bf16x8 bfrag(const u32x4* __restrict__ wf, int idx) {
    frag_u f;
    f.u = wf[idx];
    return f.b;
}

// A-fragment (16x16x32 layout: lane holds A[m=lane&15][kb..kb+7]) as hi/lo bf16 split.
__device__ __forceinline__ void make_afrag_hilo(const float* rowp, int kb,
                                                bf16x8* hi, bf16x8* lo) {
    float4 v0 = *(const float4*)(rowp + kb);
    float4 v1 = *(const float4*)(rowp + kb + 4);
    float vv[8] = {v0.x, v0.y, v0.z, v0.w, v1.x, v1.y, v1.z, v1.w};
    frag_u h, l;
    #pragma unroll
    for (int e = 0; e < 8; ++e) {
        unsigned short hb = f2bf(vv[e]);
        h.us[e] = hb;
        float hf = __uint_as_float(((unsigned)hb) << 16);
        l.us[e] = f2bf(vv[e] - hf);
    }
    *hi = h.b;
    *lo = l.b;
}

// ---------- CSR build (dst-range x XCD partitioned) ----------
// blockIdx % 8 round-robins across the 8 XCDs; range r = blockIdx % 8 means all
// atomics/stores for dst in [r*DRANGE, (r+1)*DRANGE) are issued from one XCD, so
// the deg/cursor slices and the CSR sub-region stay resident in that XCD's L2
// until lines are fully written (kills the 16x partial-line write amplification).
// Every range is covered exactly once regardless of actual placement -> correct
// under any blockIdx->XCD mapping; only speed depends on it.
__global__ __launch_bounds__(256) void deg_count_part(const int* __restrict__ dst,
                                                      int* __restrict__ deg) {
    int r = blockIdx.x & (NXCD - 1);
    int k = blockIdx.x >> 3;
    int K = gridDim.x >> 3;
    int lo = r * DRANGE;
    const int4* d4 = (const int4*)dst;
    int i = k * 256 + threadIdx.x;
    int stride = K * 256;
    for (; i < NE / 4; i += stride) {
        int4 d = d4[i];
        if ((unsigned)(d.x - lo) < (unsigned)DRANGE) atomicAdd(&deg[d.x], 1);
        if ((unsigned)(d.y - lo) < (unsigned)DRANGE) atomicAdd(&deg[d.y], 1);
        if ((unsigned)(d.z - lo) < (unsigned)DRANGE) atomicAdd(&deg[d.z], 1);
        if ((unsigned)(d.w - lo) < (unsigned)DRANGE) atomicAdd(&deg[d.w], 1);
    }
}

__global__ __launch_bounds__(256) void scan1_kernel(const int* __restrict__ deg,
                                                    int* __restrict__ bsum) {
    __shared__ int sh[256];
    int t = threadIdx.x;
    int base = blockIdx.x * SCAN_CHUNK + t * 8;
    int s = 0;
    #pragma unroll
    for (int j = 0; j < 8; ++j) {
        int idx = base + j;
        s += (idx < NU) ? deg[idx] : 0;
    }
    sh[t] = s;
    __syncthreads();
    for (int off = 128; off > 0; off >>= 1) {
        if (t < off) sh[t] += sh[t + off];
        __syncthreads();
    }
    if (t == 0) bsum[blockIdx.x] = sh[0];
}

__global__ void scan2_kernel(int* __restrict__ bsum) {
    if (threadIdx.x == 0) {
        int acc = 0;
        for (int i = 0; i < SCAN_NBLK; ++i) {
            int v = bsum[i];
            bsum[i] = acc;
            acc += v;
        }
    }
}

__global__ __launch_bounds__(256) void scan3_kernel(const int* __restrict__ deg,
                                                    const int* __restrict__ bsum,
                                                    int* __restrict__ row_start,
                                                    int* __restrict__ cursor) {
    __shared__ int sh[256];
    int t = threadIdx.x;
    int base = blockIdx.x * SCAN_CHUNK + t * 8;
    int v[8];
    int s = 0;
    #pragma unroll
    for (int j = 0; j < 8; ++j) {
        int idx = base + j;
        v[j] = (idx < NU) ? deg[idx] : 0;
        s += v[j];
    }
    sh[t] = s;
    __syncthreads();
    for (int off = 1; off < 256; off <<= 1) {
        int val = sh[t];
        int add = (t >= off) ? sh[t - off] : 0;
        __syncthreads();
        sh[t] = val + add;
        __syncthreads();
    }
    int excl = sh[t] - s + bsum[blockIdx.x];
    #pragma unroll
    for (int j = 0; j < 8; ++j) {
        int idx = base + j;
        if (idx < NU) {
            row_start[idx] = excl;
            cursor[idx] = excl;
        }
        excl += v[j];
    }
}

__global__ __launch_bounds__(256) void fill_part(const int* __restrict__ src,
                                                 const int* __restrict__ dst,
                                                 int* __restrict__ cursor,
                                                 int* __restrict__ edge_src) {
    int r = blockIdx.x & (NXCD - 1);
    int k = blockIdx.x >> 3;
    int K = gridDim.x >> 3;
    int lo = r * DRANGE;
    const int4* d4 = (const int4*)dst;
    const int4* s4 = (const int4*)src;
    int i = k * 256 + threadIdx.x;
    int stride = K * 256;
    for (; i < NE / 4; i += stride) {
        int4 d = d4[i];
        int4 s = s4[i];
        if ((unsigned)(d.x - lo) < (unsigned)DRANGE) edge_src[atomicAdd(&cursor[d.x], 1)] = s.x;
        if ((unsigned)(d.y - lo) < (unsigned)DRANGE) edge_src[atomicAdd(&cursor[d.y], 1)] = s.y;
        if ((unsigned)(d.z - lo) < (unsigned)DRANGE) edge_src[atomicAdd(&cursor[d.z], 1)] = s.z;
        if ((unsigned)(d.w - lo) < (unsigned)DRANGE) edge_src[atomicAdd(&cursor[d.w], 1)] = s.w;
    }
}

// ---------- weight pre-swizzle: global fp32 [k][n] -> bf16 B-fragments ----------
// entry idx = matg*2048 + (j*4+kk)*64 + lane ; holds B[kb..kb+7][n] with
// n = j*16 + (lane&15), kb = kk*32 + (lane>>4)*8. 6 matrices, 12288 entries.
__global__ __launch_bounds__(256) void pack_swizzle_kernel(
    const float* __restrict__ Ws0, const float* __restrict__ Wn0,
    const float* __restrict__ Ws1, const float* __restrict__ Wn1,
    const float* __restrict__ Wi0, const float* __restrict__ Wi1,
    u32x4* __restrict__ wfrag) {
    int i = blockIdx.x * 256 + threadIdx.x;  // grid 48 -> 12288
    const float* tab[6] = {Ws0, Wn0, Ws1, Wn1, Wi0, Wi1};
    int matg = i >> 11;
    int j = (i >> 8) & 7, kk = (i >> 6) & 3, ln = i & 63;
    const float* W = tab[matg];
    int n = j * 16 + (ln & 15);
    int kb = kk * 32 + (ln >> 4) * 8;
    unsigned short u[8];
    #pragma unroll
    for (int e = 0; e < 8; ++e) u[e] = f2bf(W[(size_t)(kb + e) * DD + n]);
    u32x4 w;
    w[0] = u[0] | ((unsigned)u[1] << 16);
    w[1] = u[2] | ((unsigned)u[3] << 16);
    w[2] = u[4] | ((unsigned)u[5] << 16);
    w[3] = u[6] | ((unsigned)u[7] << 16);
    wfrag[i] = w;
}

// ---------- ufeat fp32 -> packed bf16 pairs ----------
__global__ __launch_bounds__(256) void cvt_kernel(const float* __restrict__ uf,
                                                  unsigned* __restrict__ ubf) {
    int i = blockIdx.x * 256 + threadIdx.x;  // grid 25000 -> NU*64 exact
    float2 v = ((const float2*)uf)[i];
    ubf[i] = pack_bf16_pair(v.x, v.y);
}

// ---------- layer-1 aggregation (bf16 gather, bf16 mean out) ----------
__global__ __launch_bounds__(256) void agg_kernel(const unsigned* __restrict__ ubf,
                                                  const int* __restrict__ row_start,
                                                  const int* __restrict__ deg,
                                                  const int* __restrict__ edge_src,
                                                  unsigned* __restrict__ hn) {
    int wid = blockIdx.x * 4 + (threadIdx.x >> 6);
    int lane = threadIdx.x & 63;
    if (wid >= NU) return;
    int st = row_start[wid];
    int dg = deg[wid];
    int en = st + dg;
    float ax = 0.f, ay = 0.f;
    int e = st;
    for (; e + 4 <= en; e += 4) {
        int s0 = edge_src[e], s1 = edge_src[e + 1], s2 = edge_src[e + 2], s3 = edge_src[e + 3];
        float2 v0 = unpack_bf16_pair(ubf[(size_t)s0 * 64 + lane]);
        float2 v1 = unpack_bf16_pair(ubf[(size_t)s1 * 64 + lane]);
        float2 v2 = unpack_bf16_pair(ubf[(size_t)s2 * 64 + lane]);
        float2 v3 = unpack_bf16_pair(ubf[(size_t)s3 * 64 + lane]);
        ax += v0.x + v1.x + v2.x + v3.x;
        ay += v0.y + v1.y + v2.y + v3.y;
    }
    for (; e < en; ++e) {
        float2 v = unpack_bf16_pair(ubf[(size_t)edge_src[e] * 64 + lane]);
        ax += v.x;
        ay += v.y;
    }
    float inv = 1.0f / fmaxf((float)dg, 1.0f);
    hn[(size_t)wid * 64 + lane] = pack_bf16_pair(ax * inv, ay * inv);
}

// ---------- user layer 1 (all rows), MFMA ----------
__global__ __launch_bounds__(256) void user_mm_mfma(
    const float* __restrict__ hself, const unsigned short* __restrict__ hn,
    const u32x4* __restrict__ wf, const float* __restrict__ bias,
    float* __restrict__ out) {
    int t = threadIdx.x;
    int lane = t & 63;
    int tile = blockIdx.x * 4 + (t >> 6);
    if (tile >= USER_TILES) return;
    int gbase = tile * 16;
    int m = lane & 15, q = lane >> 4;
    const float* selfp = hself + (size_t)(gbase + m) * DD;
    const unsigned short* neighp = hn + (size_t)(gbase + m) * DD;
    bf16x8 as_hi[4], as_lo[4], an[4];
    #pragma unroll
    for (int kk = 0; kk < 4; ++kk) {
        int kb = kk * 32 + q * 8;
        make_afrag_hilo(selfp, kb, &as_hi[kk], &as_lo[kk]);
        frag_u f;
        f.u = *(const u32x4*)(neighp + kb);  // hn already bf16: hi only
        an[kk] = f.b;
    }
    f32x4 acc[8];
    f32x4 zero = {0.f, 0.f, 0.f, 0.f};
    #pragma unroll
    for (int j = 0; j < 8; ++j) acc[j] = zero;
    #pragma unroll 2
    for (int j = 0; j < 8; ++j) {
        #pragma unroll
        for (int kk = 0; kk < 4; ++kk) {
            bf16x8 bs = bfrag(wf, (j * 4 + kk) * 64 + lane);
            acc[j] = mfma16(as_hi[kk], bs, acc[j]);
            acc[j] = mfma16(as_lo[kk], bs, acc[j]);
            bf16x8 bn = bfrag(wf, 2048 + (j * 4 + kk) * 64 + lane);
            acc[j] = mfma16(an[kk], bn, acc[j]);
        }
    }
    float ss[4] = {0.f, 0.f, 0.f, 0.f};
    #pragma unroll
    for (int j = 0; j < 8; ++j) {
        float bj = bias[j * 16 + m];
        #pragma unroll
        for (int r = 0; r < 4; ++r) {
            float x = acc[j][r] + bj;
            x = x > 0.f ? x : 0.2f * x;
            acc[j][r] = x;
            ss[r] += x * x;
        }
    }
    #pragma unroll
    for (int r = 0; r < 4; ++r) {
        float s = ss[r];
        s += __shfl_xor(s, 1, 64);
        s += __shfl_xor(s, 2, 64);
        s += __shfl_xor(s, 4, 64);
        s += __shfl_xor(s, 8, 64);
        ss[r] = 1.0f / fmaxf(sqrtf(s), 1e-12f);
    }
    #pragma unroll
    for (int j = 0; j < 8; ++j)
        #pragma unroll
        for (int r = 0; r < 4; ++r)
            out[(size_t)(gbase + q * 4 + r) * DD + j * 16 + m] = acc[j][r] * ss[r];
}

// ---------- user layer 2 (users rows): fused agg + MFMA + output ----------
__global__ __launch_bounds__(256) void user_l2_mfma(
    const float* __restrict__ ufeat, const float* __restrict__ h1,
    const int* __restrict__ users, const int* __restrict__ row_start,
    const int* __restrict__ deg, const int* __restrict__ edge_src,
    const u32x4* __restrict__ wf, const float* __restrict__ bias,
    float* __restrict__ out) {
    __shared__ float scratch[4][16 * 132];  // per-wave, stride 132 (16B-aligned rows)
    int t = threadIdx.x;
    int lane = t & 63, wave = t >> 6;
    int tile = blockIdx.x * 4 + wave;  // 1024 tiles exact
    int gb = tile * 16;
    float* sc = scratch[wave];
    // phase 1: per-row wave aggregation of h1 into scratch + copy cols 0..255
    for (int r = 0; r < 16; ++r) {
        int u = users[gb + r];
        int st = row_start[u], dg = deg[u], en = st + dg;
        float ax = 0.f, ay = 0.f;
        int e = st;
        for (; e + 4 <= en; e += 4) {
            int s0 = edge_src[e], s1 = edge_src[e + 1];
            int s2 = edge_src[e + 2], s3 = edge_src[e + 3];
            float2 v0 = ((const float2*)(h1 + (size_t)s0 * DD))[lane];
            float2 v1 = ((const float2*)(h1 + (size_t)s1 * DD))[lane];
            float2 v2 = ((const float2*)(h1 + (size_t)s2 * DD))[lane];
            float2 v3 = ((const float2*)(h1 + (size_t)s3 * DD))[lane];
            ax += v0.x + v1.x + v2.x + v3.x;
            ay += v0.y + v1.y + v2.y + v3.y;
        }
        for (; e < en; ++e) {
            float2 v = ((const float2*)(h1 + (size_t)edge_src[e] * DD))[lane];
            ax += v.x;
            ay += v.y;
        }
        float inv = 1.0f / fmaxf((float)dg, 1.0f);
        sc[r * 132 + 2 * lane] = ax * inv;
        sc[r * 132 + 2 * lane + 1] = ay * inv;
        float* orow = out + (size_t)(gb + r) * 384;
        ((float2*)orow)[lane] = ((const float2*)(ufeat + (size_t)u * DD))[lane];
        ((float2*)orow)[64 + lane] = ((const float2*)(h1 + (size_t)u * DD))[lane];
    }
    // phase 2: MFMA
    int m = lane & 15, q = lane >> 4;
    int um = users[gb + m];
    const float* selfp = h1 + (size_t)um * DD;
    bf16x8 sh[4], sl[4], nh[4], nl[4];
    #pragma unroll
    for (int kk = 0; kk < 4; ++kk) {
        int kb = kk * 32 + q * 8;
        make_afrag_hilo(selfp, kb, &sh[kk], &sl[kk]);
        make_afrag_hilo(sc + m * 132, kb, &nh[kk], &nl[kk]);
    }
    f32x4 acc[8];
    f32x4 zero = {0.f, 0.f, 0.f, 0.f};
    #pragma unroll
    for (int j = 0; j < 8; ++j) acc[j] = zero;
    #pragma unroll 2
    for (int j = 0; j < 8; ++j) {
        #pragma unroll
        for (int kk = 0; kk < 4; ++kk) {
            bf16x8 bs = bfrag(wf, (j * 4 + kk) * 64 + lane);
            acc[j] = mfma16(sh[kk], bs, acc[j]);
            acc[j] = mfma16(sl[kk], bs, acc[j]);
            bf16x8 bn = bfrag(wf, 2048 + (j * 4 + kk) * 64 + lane);
            acc[j] = mfma16(nh[kk], bn, acc[j]);
            acc[j] = mfma16(nl[kk], bn, acc[j]);
        }
    }
    float ss[4] = {0.f, 0.f, 0.f, 0.f};
    #pragma unroll
    for (int j = 0; j < 8; ++j) {
        float bj = bias[j * 16 + m];
        #pragma unroll
        for (int r = 0; r < 4; ++r) {
            float x = acc[j][r] + bj;
            x = x > 0.f ? x : 0.2f * x;
            acc[j][r] = x;
            ss[r] += x * x;
        }
    }
    #pragma unroll
    for (int r = 0; r < 4; ++r) {
        float s = ss[r];
        s += __shfl_xor(s, 1, 64);
        s += __shfl_xor(s, 2, 64);
        s += __shfl_xor(s, 4, 64);
        s += __shfl_xor(s, 8, 64);
        ss[r] = 1.0f / fmaxf(sqrtf(s), 1e-12f);
    }
    #pragma unroll
    for (int j = 0; j < 8; ++j)
        #pragma unroll
        for (int r = 0; r < 4; ++r)
            out[(size_t)(gb + q * 4 + r) * 384 + 256 + j * 16 + m] = acc[j][r] * ss[r];
}

// ---------- item side (pos|neg rows), 2 layers, MFMA ----------
__global__ __launch_bounds__(256) void item_mfma(
    const float* __restrict__ ifeat, const int* __restrict__ pos,
    const int* __restrict__ neg, const u32x4* __restrict__ wf,
    const float* __restrict__ b0, const float* __restrict__ b1,
    float* __restrict__ out) {
    __shared__ float scratch[4][16 * 132];
    int t = threadIdx.x;
    int lane = t & 63, wave = t >> 6;
    int tile = blockIdx.x * 4 + wave;  // 2048 tiles exact
    int gb = tile * 16;
    int m = lane & 15, q = lane >> 4;
    float* sc = scratch[wave];
    int rowm = gb + m;
    int idxm = (rowm < BB) ? pos[rowm] : neg[rowm - BB];
    const float* rowp = ifeat + (size_t)idxm * DD;
    bf16x8 ahi[4], alo[4];
    #pragma unroll
    for (int kk = 0; kk < 4; ++kk)
        make_afrag_hilo(rowp, kk * 32 + q * 8, &ahi[kk], &alo[kk]);
    f32x4 acc[8];
    f32x4 zero = {0.f, 0.f, 0.f, 0.f};
    #pragma unroll
    for (int j = 0; j < 8; ++j) acc[j] = zero;
    #pragma unroll 2
    for (int j = 0; j < 8; ++j) {
        #pragma unroll
        for (int kk = 0; kk < 4; ++kk) {
            bf16x8 b = bfrag(wf, (j * 4 + kk) * 64 + lane);
            acc[j] = mfma16(ahi[kk], b, acc[j]);
            acc[j] = mfma16(alo[kk], b, acc[j]);
        }
    }
    // epilogue 0 -> r1 in scratch
    float ss[4] = {0.f, 0.f, 0.f, 0.f};
    #pragma unroll
    for (int j = 0; j < 8; ++j) {
        float bj = b0[j * 16 + m];
        #pragma unroll
        for (int r = 0; r < 4; ++r) {
            float x = acc[j][r] + bj;
            x = x > 0.f ? x : 0.2f * x;
            acc[j][r] = x;
            ss[r] += x * x;
        }
    }
    #pragma unroll
    for (int r = 0; r < 4; ++r) {
        float s = ss[r];
        s += __shfl_xor(s, 1, 64);
        s += __shfl_xor(s, 2, 64);
        s += __shfl_xor(s, 4, 64);
        s += __shfl_xor(s, 8, 64);
        ss[r] = 1.0f / fmaxf(sqrtf(s), 1e-12f);
    }
    #pragma unroll
    for (int j = 0; j < 8; ++j)
        #pragma unroll
        for (int r = 0; r < 4; ++r)
            sc[(q * 4 + r) * 132 + j * 16 + m] = acc[j][r] * ss[r];
    // copy r0 (raw gathered ifeat) and r1 (from scratch) to output
    for (int r = 0; r < 16; ++r) {
        int row = gb + r;
        int idx = (row < BB) ? pos[row] : neg[row - BB];
        float* orow = out + (size_t)(BB + row) * 384;  // pos b -> BB+b, neg b' -> 2BB+b' == BB+row
        ((float2*)orow)[lane] = ((const float2*)(ifeat + (size_t)idx * DD))[lane];
        float2 r1v;
        r1v.x = sc[r * 132 + 2 * lane];
        r1v.y = sc[r * 132 + 2 * lane + 1];
        ((float2*)orow)[64 + lane] = r1v;
    }
    // layer 1: A-frags from scratch
    bf16x8 chi[4], clo[4];
    #pragma unroll
    for (int kk = 0; kk < 4; ++kk)
        make_afrag_hilo(sc + m * 132, kk * 32 + q * 8, &chi[kk], &clo[kk]);
    #pragma unroll
    for (int j = 0; j < 8; ++j) acc[j] = zero;
    #pragma unroll 2
    for (int j = 0; j < 8; ++j) {
        #pragma unroll
        for (int kk = 0; kk < 4; ++kk) {
            bf16x8 b = bfrag(wf, 2048 + (j * 4 + kk) * 64 + lane);
            acc[j] = mfma16(chi[kk], b, acc[j]);
            acc[j] = mfma16(clo[kk], b, acc[j]);
        }
    }
    float ss1[4] = {0.f, 0.f, 0.f, 0.f};
    #pragma unroll
    for (int j = 0; j < 8; ++j) {
        float bj = b1[j * 16 + m];
        #pragma unroll
        for (int r = 0; r < 4; ++r) {
            float x = acc[j][r] + bj;
            x = x > 0.f ? x : 0.2f * x;
            acc[j][r] = x;
            ss1[r] += x * x;
        }
    }
    #pragma unroll
    for (int r = 0; r < 4; ++r) {
        float s = ss1[r];
        s += __shfl_xor(s, 1, 64);
        s += __shfl_xor(s, 2, 64);
        s += __shfl_xor(s, 4, 64);
        s += __shfl_xor(s, 8, 64);
        ss1[r] = 1.0f / fmaxf(sqrtf(s), 1e-12f);
    }
    #pragma unroll
    for (int j = 0; j < 8; ++j)
        #pragma unroll
        for (int r = 0; r < 4; ++r)
            out[(size_t)(BB + gb + q * 4 + r) * 384 + 256 + j * 16 + m] = acc[j][r] * ss1[r];
}

extern "C" void kernel_launch(void* const* d_in, const int* in_sizes, int n_in,
                              void* d_out, int out_size, void* d_ws, size_t ws_size,
                              hipStream_t stream) {
    const int* src = (const int*)d_in[0];
    const int* dst = (const int*)d_in[1];
    const int* users = (const int*)d_in[2];
    const int* pos = (const int*)d_in[3];
    const int* neg = (const int*)d_in[4];
    const float* ufeat = (const float*)d_in[5];
    const float* ifeat = (const float*)d_in[6];
    const float* Ws0 = (const float*)d_in[7];
    const float* Wn0 = (const float*)d_in[8];
    const float* bu0 = (const float*)d_in[9];
    const float* Wi0 = (const float*)d_in[10];
    const float* bi0 = (const float*)d_in[11];
    const float* Ws1 = (const float*)d_in[12];
    const float* Wn1 = (const float*)d_in[13];
    const float* bu1 = (const float*)d_in[14];
    const float* Wi1 = (const float*)d_in[15];
    const float* bi1 = (const float*)d_in[16];
    float* out = (float*)d_out;

    char* ws = (char*)d_ws;
    int* deg = (int*)(ws + OFF_DEG);
    int* row_start = (int*)(ws + OFF_ROWSTART);
    int* cursor = (int*)(ws + OFF_CURSOR);
    int* bsum = (int*)(ws + OFF_BSUM);
    int* edge_src = (int*)(ws + OFF_EDGESRC);
    float* h1 = (float*)(ws + OFF_H1);
    u32x4* wfrag = (u32x4*)(ws + OFF_WFRAG);

    unsigned* ubf = (unsigned*)d_out;                                    // bf16 ufeat
    unsigned* hn = (unsigned*)((char*)d_out + (size_t)NU * DD * 2);      // bf16 neighbor mean
    const unsigned short* hn_us = (const unsigned short*)hn;

    hipMemsetAsync(deg, 0, NU * sizeof(int), stream);
    pack_swizzle_kernel<<<48, 256, 0, stream>>>(Ws0, Wn0, Ws1, Wn1, Wi0, Wi1, wfrag);
    deg_count_part<<<NXCD * PART_K, 256, 0, stream>>>(dst, deg);
    scan1_kernel<<<SCAN_NBLK, 256, 0, stream>>>(deg, bsum);
    scan2_kernel<<<1, 64, 0, stream>>>(bsum);
    scan3_kernel<<<SCAN_NBLK, 256, 0, stream>>>(deg, bsum, row_start, cursor);
    fill_part<<<NXCD * PART_K, 256, 0, stream>>>(src, dst, cursor, edge_src);
    cvt_kernel<<<NU * 64 / 256, 256, 0, stream>>>(ufeat, ubf);
    agg_kernel<<<(NU + 3) / 4, 256, 0, stream>>>(ubf, row_start, deg, edge_src, hn);
    user_mm_mfma<<<(USER_TILES + 3) / 4, 256, 0, stream>>>(ufeat, hn_us, wfrag, bu0, h1);
    user_l2_mfma<<<BB / 64, 256, 0, stream>>>(ufeat, h1, users, row_start, deg, edge_src,
                                              wfrag + 4096, bu1, out);
    item_mfma<<<2 * BB / 64, 256, 0, stream>>>(ifeat, pos, neg, wfrag + 8192, bi0, bi1, out);
}

// Round 2
// 536.743 us; speedup vs baseline: 1.1373x; 1.0506x over previous
//
#include <hip/hip_runtime.h>

#define NU 100000
#define NI 100000
#define NE 1600000
#define BB 16384
#define DD 128

static constexpr int SCAN_CHUNK = 2048;                       // 256 threads * 8
static constexpr int SCAN_NBLK  = (NU + SCAN_CHUNK - 1) / SCAN_CHUNK; // 49
static constexpr int USER_TILES = NU / 16;                    // 6250

static constexpr int NXCD   = 8;
static constexpr int DRANGE = NU / NXCD;                      // 12500 dsts per XCD range
static constexpr int PART_K = 128;                            // sub-blocks per range

// ---------- workspace layout (bytes) ----------
static constexpr size_t OFF_DEG      = 0;          // int[NU]   400000
static constexpr size_t OFF_ROWSTART = 400128;     // int[NU]
static constexpr size_t OFF_CURSOR   = 800256;     // int[NU]
static constexpr size_t OFF_BSUM     = 1200384;    // int[64]
static constexpr size_t OFF_EDGESRC  = 1200640;    // int[NE]   6400000
static constexpr size_t OFF_H1       = 7600640;    // float[NU*DD] 51200000
static constexpr size_t OFF_WFRAG    = 58800640;   // u32x4[12288] 196608 (pre-swizzled bf16 weights)
// end = 58,997,248 bytes

// d_out staging (dead before real outputs are written):
//   ubf   at d_out+0        : uint[NU*64]  25.6 MB  (ufeat in bf16 pairs)
//   hn_bf at d_out+25.6MB   : ushort[NU*128] 25.6 MB (neighbor mean, bf16)
// user_l2 writes rows 0..BB-1 (bytes 0..25.2M, ubf dead by then);
// item writes rows BB..3BB-1 (overlaps hn_bf region, dead by then).

typedef __bf16 bf16x8 __attribute__((ext_vector_type(8)));
typedef float f32x4 __attribute__((ext_vector_type(4)));
typedef unsigned int u32x4 __attribute__((ext_vector_type(4)));

union frag_u {
    u32x4 u;
    bf16x8 b;
    unsigned short us[8];
};

// ---------- helpers ----------
__device__ __forceinline__ unsigned short f2bf(float f) {
    unsigned u = __float_as_uint(f);
    u = (u + 0x7fffu + ((u >> 16) & 1u)) >> 16;  // RNE
    return (unsigned short)u;
}

__device__ __forceinline__ unsigned pack_bf16_pair(float a, float b) {
    return (unsigned)f2bf(a) | ((unsigned)f2bf(b) << 16);
}

__device__ __forceinline__ float2 unpack_bf16_pair(unsigned u) {
    float2 r;
    r.x = __uint_as_float(u << 16);
    r.y = __uint_as_float(u & 0xffff0000u);
    return r;
}

__device__ __forceinline__ f32x4 mfma16(bf16x8 a, bf16x8 b, f32x4 c) {
    return __builtin_amdgcn_mfma_f32_16x16x32_bf16(a, b, c, 0, 0, 0);
}

__device__ __forceinline__ bf16x8 bfrag(const u32x4* __restrict__ wf, int idx) {
    frag_u f;
    f.u = wf[idx];
    return f.b;
}

// A-fragment (16x16x32 layout: lane holds A[m=lane&15][kb..kb+7]) as hi/lo bf16 split.
__device__ __forceinline__ void make_afrag_hilo(const float* rowp, int kb,
                                                bf16x8* hi, bf16x8* lo) {
    float4 v0 = *(const float4*)(rowp + kb);
    float4 v1 = *(const float4*)(rowp + kb + 4);
    float vv[8] = {v0.x, v0.y, v0.z, v0.w, v1.x, v1.y, v1.z, v1.w};
    frag_u h, l;
    #pragma unroll
    for (int e = 0; e < 8; ++e) {
        unsigned short hb = f2bf(vv[e]);
        h.us[e] = hb;
        float hf = __uint_as_float(((unsigned)hb) << 16);
        l.us[e] = f2bf(vv[e] - hf);
    }
    *hi = h.b;
    *lo = l.b;
}

// ---------- CSR build (dst-range x XCD partitioned) ----------
// blockIdx % 8 round-robins across the 8 XCDs; range r = blockIdx % 8 means all
// atomics/stores for dst in [r*DRANGE, (r+1)*DRANGE) are issued from one XCD, so
// the deg/cursor slices and the CSR sub-region stay resident in that XCD's L2
// until lines are fully written (kills the 16x partial-line write amplification).
// Every range is covered exactly once regardless of actual placement -> correct
// under any blockIdx->XCD mapping; only speed depends on it.
__global__ __launch_bounds__(256) void deg_count_part(const int* __restrict__ dst,
                                                      int* __restrict__ deg) {
    int r = blockIdx.x & (NXCD - 1);
    int k = blockIdx.x >> 3;
    int K = gridDim.x >> 3;
    int lo = r * DRANGE;
    const int4* d4 = (const int4*)dst;
    int i = k * 256 + threadIdx.x;
    int stride = K * 256;
    for (; i < NE / 4; i += stride) {
        int4 d = d4[i];
        if ((unsigned)(d.x - lo) < (unsigned)DRANGE) atomicAdd(&deg[d.x], 1);
        if ((unsigned)(d.y - lo) < (unsigned)DRANGE) atomicAdd(&deg[d.y], 1);
        if ((unsigned)(d.z - lo) < (unsigned)DRANGE) atomicAdd(&deg[d.z], 1);
        if ((unsigned)(d.w - lo) < (unsigned)DRANGE) atomicAdd(&deg[d.w], 1);
    }
}

__global__ __launch_bounds__(256) void scan1_kernel(const int* __restrict__ deg,
                                                    int* __restrict__ bsum) {
    __shared__ int sh[256];
    int t = threadIdx.x;
    int base = blockIdx.x * SCAN_CHUNK + t * 8;
    int s = 0;
    #pragma unroll
    for (int j = 0; j < 8; ++j) {
        int idx = base + j;
        s += (idx < NU) ? deg[idx] : 0;
    }
    sh[t] = s;
    __syncthreads();
    for (int off = 128; off > 0; off >>= 1) {
        if (t < off) sh[t] += sh[t + off];
        __syncthreads();
    }
    if (t == 0) bsum[blockIdx.x] = sh[0];
}

__global__ void scan2_kernel(int* __restrict__ bsum) {
    if (threadIdx.x == 0) {
        int acc = 0;
        for (int i = 0; i < SCAN_NBLK; ++i) {
            int v = bsum[i];
            bsum[i] = acc;
            acc += v;
        }
    }
}

__global__ __launch_bounds__(256) void scan3_kernel(const int* __restrict__ deg,
                                                    const int* __restrict__ bsum,
                                                    int* __restrict__ row_start,
                                                    int* __restrict__ cursor) {
    __shared__ int sh[256];
    int t = threadIdx.x;
    int base = blockIdx.x * SCAN_CHUNK + t * 8;
    int v[8];
    int s = 0;
    #pragma unroll
    for (int j = 0; j < 8; ++j) {
        int idx = base + j;
        v[j] = (idx < NU) ? deg[idx] : 0;
        s += v[j];
    }
    sh[t] = s;
    __syncthreads();
    for (int off = 1; off < 256; off <<= 1) {
        int val = sh[t];
        int add = (t >= off) ? sh[t - off] : 0;
        __syncthreads();
        sh[t] = val + add;
        __syncthreads();
    }
    int excl = sh[t] - s + bsum[blockIdx.x];
    #pragma unroll
    for (int j = 0; j < 8; ++j) {
        int idx = base + j;
        if (idx < NU) {
            row_start[idx] = excl;
            cursor[idx] = excl;
        }
        excl += v[j];
    }
}

__global__ __launch_bounds__(256) void fill_part(const int* __restrict__ src,
                                                 const int* __restrict__ dst,
                                                 int* __restrict__ cursor,
                                                 int* __restrict__ edge_src) {
    int r = blockIdx.x & (NXCD - 1);
    int k = blockIdx.x >> 3;
    int K = gridDim.x >> 3;
    int lo = r * DRANGE;
    const int4* d4 = (const int4*)dst;
    const int4* s4 = (const int4*)src;
    int i = k * 256 + threadIdx.x;
    int stride = K * 256;
    for (; i < NE / 4; i += stride) {
        int4 d = d4[i];
        int4 s = s4[i];
        if ((unsigned)(d.x - lo) < (unsigned)DRANGE) edge_src[atomicAdd(&cursor[d.x], 1)] = s.x;
        if ((unsigned)(d.y - lo) < (unsigned)DRANGE) edge_src[atomicAdd(&cursor[d.y], 1)] = s.y;
        if ((unsigned)(d.z - lo) < (unsigned)DRANGE) edge_src[atomicAdd(&cursor[d.z], 1)] = s.z;
        if ((unsigned)(d.w - lo) < (unsigned)DRANGE) edge_src[atomicAdd(&cursor[d.w], 1)] = s.w;
    }
}

// ---------- weight pre-swizzle: global fp32 [k][n] -> bf16 B-fragments ----------
// entry idx = matg*2048 + (j*4+kk)*64 + lane ; holds B[kb..kb+7][n] with
// n = j*16 + (lane&15), kb = kk*32 + (lane>>4)*8. 6 matrices, 12288 entries.
__global__ __launch_bounds__(256) void pack_swizzle_kernel(
    const float* __restrict__ Ws0, const float* __restrict__ Wn0,
    const float* __restrict__ Ws1, const float* __restrict__ Wn1,
    const float* __restrict__ Wi0, const float* __restrict__ Wi1,
    u32x4* __restrict__ wfrag) {
    int i = blockIdx.x * 256 + threadIdx.x;  // grid 48 -> 12288
    const float* tab[6] = {Ws0, Wn0, Ws1, Wn1, Wi0, Wi1};
    int matg = i >> 11;
    int j = (i >> 8) & 7, kk = (i >> 6) & 3, ln = i & 63;
    const float* W = tab[matg];
    int n = j * 16 + (ln & 15);
    int kb = kk * 32 + (ln >> 4) * 8;
    unsigned short u[8];
    #pragma unroll
    for (int e = 0; e < 8; ++e) u[e] = f2bf(W[(size_t)(kb + e) * DD + n]);
    u32x4 w;
    w[0] = u[0] | ((unsigned)u[1] << 16);
    w[1] = u[2] | ((unsigned)u[3] << 16);
    w[2] = u[4] | ((unsigned)u[5] << 16);
    w[3] = u[6] | ((unsigned)u[7] << 16);
    wfrag[i] = w;
}

// ---------- ufeat fp32 -> packed bf16 pairs ----------
__global__ __launch_bounds__(256) void cvt_kernel(const float* __restrict__ uf,
                                                  unsigned* __restrict__ ubf) {
    int i = blockIdx.x * 256 + threadIdx.x;  // grid 25000 -> NU*64 exact
    float2 v = ((const float2*)uf)[i];
    ubf[i] = pack_bf16_pair(v.x, v.y);
}

// ---------- layer-1 aggregation (bf16 gather, bf16 mean out) ----------
__global__ __launch_bounds__(256) void agg_kernel(const unsigned* __restrict__ ubf,
                                                  const int* __restrict__ row_start,
                                                  const int* __restrict__ deg,
                                                  const int* __restrict__ edge_src,
                                                  unsigned* __restrict__ hn) {
    int wid = blockIdx.x * 4 + (threadIdx.x >> 6);
    int lane = threadIdx.x & 63;
    if (wid >= NU) return;
    int st = row_start[wid];
    int dg = deg[wid];
    int en = st + dg;
    float ax = 0.f, ay = 0.f;
    int e = st;
    for (; e + 4 <= en; e += 4) {
        int s0 = edge_src[e], s1 = edge_src[e + 1], s2 = edge_src[e + 2], s3 = edge_src[e + 3];
        float2 v0 = unpack_bf16_pair(ubf[(size_t)s0 * 64 + lane]);
        float2 v1 = unpack_bf16_pair(ubf[(size_t)s1 * 64 + lane]);
        float2 v2 = unpack_bf16_pair(ubf[(size_t)s2 * 64 + lane]);
        float2 v3 = unpack_bf16_pair(ubf[(size_t)s3 * 64 + lane]);
        ax += v0.x + v1.x + v2.x + v3.x;
        ay += v0.y + v1.y + v2.y + v3.y;
    }
    for (; e < en; ++e) {
        float2 v = unpack_bf16_pair(ubf[(size_t)edge_src[e] * 64 + lane]);
        ax += v.x;
        ay += v.y;
    }
    float inv = 1.0f / fmaxf((float)dg, 1.0f);
    hn[(size_t)wid * 64 + lane] = pack_bf16_pair(ax * inv, ay * inv);
}

// ---------- user layer 1 (all rows), MFMA ----------
__global__ __launch_bounds__(256) void user_mm_mfma(
    const float* __restrict__ hself, const unsigned short* __restrict__ hn,
    const u32x4* __restrict__ wf, const float* __restrict__ bias,
    float* __restrict__ out) {
    int t = threadIdx.x;
    int lane = t & 63;
    int tile = blockIdx.x * 4 + (t >> 6);
    if (tile >= USER_TILES) return;
    int gbase = tile * 16;
    int m = lane & 15, q = lane >> 4;
    const float* selfp = hself + (size_t)(gbase + m) * DD;
    const unsigned short* neighp = hn + (size_t)(gbase + m) * DD;
    bf16x8 as_hi[4], as_lo[4], an[4];
    #pragma unroll
    for (int kk = 0; kk < 4; ++kk) {
        int kb = kk * 32 + q * 8;
        make_afrag_hilo(selfp, kb, &as_hi[kk], &as_lo[kk]);
        frag_u f;
        f.u = *(const u32x4*)(neighp + kb);  // hn already bf16: hi only
        an[kk] = f.b;
    }
    f32x4 acc[8];
    f32x4 zero = {0.f, 0.f, 0.f, 0.f};
    #pragma unroll
    for (int j = 0; j < 8; ++j) acc[j] = zero;
    #pragma unroll 2
    for (int j = 0; j < 8; ++j) {
        #pragma unroll
        for (int kk = 0; kk < 4; ++kk) {
            bf16x8 bs = bfrag(wf, (j * 4 + kk) * 64 + lane);
            acc[j] = mfma16(as_hi[kk], bs, acc[j]);
            acc[j] = mfma16(as_lo[kk], bs, acc[j]);
            bf16x8 bn = bfrag(wf, 2048 + (j * 4 + kk) * 64 + lane);
            acc[j] = mfma16(an[kk], bn, acc[j]);
        }
    }
    float ss[4] = {0.f, 0.f, 0.f, 0.f};
    #pragma unroll
    for (int j = 0; j < 8; ++j) {
        float bj = bias[j * 16 + m];
        #pragma unroll
        for (int r = 0; r < 4; ++r) {
            float x = acc[j][r] + bj;
            x = x > 0.f ? x : 0.2f * x;
            acc[j][r] = x;
            ss[r] += x * x;
        }
    }
    #pragma unroll
    for (int r = 0; r < 4; ++r) {
        float s = ss[r];
        s += __shfl_xor(s, 1, 64);
        s += __shfl_xor(s, 2, 64);
        s += __shfl_xor(s, 4, 64);
        s += __shfl_xor(s, 8, 64);
        ss[r] = 1.0f / fmaxf(sqrtf(s), 1e-12f);
    }
    #pragma unroll
    for (int j = 0; j < 8; ++j)
        #pragma unroll
        for (int r = 0; r < 4; ++r)
            out[(size_t)(gbase + q * 4 + r) * DD + j * 16 + m] = acc[j][r] * ss[r];
}

// ---------- user layer 2 (users rows): fused agg + MFMA + output ----------
// One block per 16-row tile (grid 1024 = 4 blocks/CU, 16 waves/CU for the
// gather phase). 4 waves split phase 1 (4 rows each) into block scratch;
// wave 0 then runs the small MFMA+epilogue phase.
__global__ __launch_bounds__(256) void user_l2_mfma(
    const float* __restrict__ ufeat, const float* __restrict__ h1,
    const int* __restrict__ users, const int* __restrict__ row_start,
    const int* __restrict__ deg, const int* __restrict__ edge_src,
    const u32x4* __restrict__ wf, const float* __restrict__ bias,
    float* __restrict__ out) {
    __shared__ float sc[16 * 132];  // block-level, stride 132 (16B-aligned rows)
    int t = threadIdx.x;
    int lane = t & 63, wave = t >> 6;
    int tile = blockIdx.x;  // 1024 tiles exact
    int gb = tile * 16;
    // phase 1: each wave aggregates 4 rows of h1 into scratch + copies cols 0..255
    #pragma unroll
    for (int rr = 0; rr < 4; ++rr) {
        int r = wave * 4 + rr;
        int u = users[gb + r];
        int st = row_start[u], dg = deg[u], en = st + dg;
        float ax = 0.f, ay = 0.f;
        int e = st;
        for (; e + 4 <= en; e += 4) {
            int s0 = edge_src[e], s1 = edge_src[e + 1];
            int s2 = edge_src[e + 2], s3 = edge_src[e + 3];
            float2 v0 = ((const float2*)(h1 + (size_t)s0 * DD))[lane];
            float2 v1 = ((const float2*)(h1 + (size_t)s1 * DD))[lane];
            float2 v2 = ((const float2*)(h1 + (size_t)s2 * DD))[lane];
            float2 v3 = ((const float2*)(h1 + (size_t)s3 * DD))[lane];
            ax += v0.x + v1.x + v2.x + v3.x;
            ay += v0.y + v1.y + v2.y + v3.y;
        }
        for (; e < en; ++e) {
            float2 v = ((const float2*)(h1 + (size_t)edge_src[e] * DD))[lane];
            ax += v.x;
            ay += v.y;
        }
        float inv = 1.0f / fmaxf((float)dg, 1.0f);
        sc[r * 132 + 2 * lane] = ax * inv;
        sc[r * 132 + 2 * lane + 1] = ay * inv;
        float* orow = out + (size_t)(gb + r) * 384;
        ((float2*)orow)[lane] = ((const float2*)(ufeat + (size_t)u * DD))[lane];
        ((float2*)orow)[64 + lane] = ((const float2*)(h1 + (size_t)u * DD))[lane];
    }
    __syncthreads();
    if (wave != 0) return;
    // phase 2: MFMA (wave 0 only -- ~128 MFMAs, tiny vs the gather phase)
    int m = lane & 15, q = lane >> 4;
    int um = users[gb + m];
    const float* selfp = h1 + (size_t)um * DD;
    bf16x8 sh[4], sl[4], nh[4], nl[4];
    #pragma unroll
    for (int kk = 0; kk < 4; ++kk) {
        int kb = kk * 32 + q * 8;
        make_afrag_hilo(selfp, kb, &sh[kk], &sl[kk]);
        make_afrag_hilo(sc + m * 132, kb, &nh[kk], &nl[kk]);
    }
    f32x4 acc[8];
    f32x4 zero = {0.f, 0.f, 0.f, 0.f};
    #pragma unroll
    for (int j = 0; j < 8; ++j) acc[j] = zero;
    #pragma unroll 2
    for (int j = 0; j < 8; ++j) {
        #pragma unroll
        for (int kk = 0; kk < 4; ++kk) {
            bf16x8 bs = bfrag(wf, (j * 4 + kk) * 64 + lane);
            acc[j] = mfma16(sh[kk], bs, acc[j]);
            acc[j] = mfma16(sl[kk], bs, acc[j]);
            bf16x8 bn = bfrag(wf, 2048 + (j * 4 + kk) * 64 + lane);
            acc[j] = mfma16(nh[kk], bn, acc[j]);
            acc[j] = mfma16(nl[kk], bn, acc[j]);
        }
    }
    float ss[4] = {0.f, 0.f, 0.f, 0.f};
    #pragma unroll
    for (int j = 0; j < 8; ++j) {
        float bj = bias[j * 16 + m];
        #pragma unroll
        for (int r = 0; r < 4; ++r) {
            float x = acc[j][r] + bj;
            x = x > 0.f ? x : 0.2f * x;
            acc[j][r] = x;
            ss[r] += x * x;
        }
    }
    #pragma unroll
    for (int r = 0; r < 4; ++r) {
        float s = ss[r];
        s += __shfl_xor(s, 1, 64);
        s += __shfl_xor(s, 2, 64);
        s += __shfl_xor(s, 4, 64);
        s += __shfl_xor(s, 8, 64);
        ss[r] = 1.0f / fmaxf(sqrtf(s), 1e-12f);
    }
    #pragma unroll
    for (int j = 0; j < 8; ++j)
        #pragma unroll
        for (int r = 0; r < 4; ++r)
            out[(size_t)(gb + q * 4 + r) * 384 + 256 + j * 16 + m] = acc[j][r] * ss[r];
}

// ---------- item side (pos|neg rows), 2 layers, MFMA ----------
__global__ __launch_bounds__(256) void item_mfma(
    const float* __restrict__ ifeat, const int* __restrict__ pos,
    const int* __restrict__ neg, const u32x4* __restrict__ wf,
    const float* __restrict__ b0, const float* __restrict__ b1,
    float* __restrict__ out) {
    __shared__ float scratch[4][16 * 132];
    int t = threadIdx.x;
    int lane = t & 63, wave = t >> 6;
    int tile = blockIdx.x * 4 + wave;  // 2048 tiles exact
    int gb = tile * 16;
    int m = lane & 15, q = lane >> 4;
    float* sc = scratch[wave];
    int rowm = gb + m;
    int idxm = (rowm < BB) ? pos[rowm] : neg[rowm - BB];
    const float* rowp = ifeat + (size_t)idxm * DD;
    bf16x8 ahi[4], alo[4];
    #pragma unroll
    for (int kk = 0; kk < 4; ++kk)
        make_afrag_hilo(rowp, kk * 32 + q * 8, &ahi[kk], &alo[kk]);
    f32x4 acc[8];
    f32x4 zero = {0.f, 0.f, 0.f, 0.f};
    #pragma unroll
    for (int j = 0; j < 8; ++j) acc[j] = zero;
    #pragma unroll 2
    for (int j = 0; j < 8; ++j) {
        #pragma unroll
        for (int kk = 0; kk < 4; ++kk) {
            bf16x8 b = bfrag(wf, (j * 4 + kk) * 64 + lane);
            acc[j] = mfma16(ahi[kk], b, acc[j]);
            acc[j] = mfma16(alo[kk], b, acc[j]);
        }
    }
    // epilogue 0 -> r1 in scratch
    float ss[4] = {0.f, 0.f, 0.f, 0.f};
    #pragma unroll
    for (int j = 0; j < 8; ++j) {
        float bj = b0[j * 16 + m];
        #pragma unroll
        for (int r = 0; r < 4; ++r) {
            float x = acc[j][r] + bj;
            x = x > 0.f ? x : 0.2f * x;
            acc[j][r] = x;
            ss[r] += x * x;
        }
    }
    #pragma unroll
    for (int r = 0; r < 4; ++r) {
        float s = ss[r];
        s += __shfl_xor(s, 1, 64);
        s += __shfl_xor(s, 2, 64);
        s += __shfl_xor(s, 4, 64);
        s += __shfl_xor(s, 8, 64);
        ss[r] = 1.0f / fmaxf(sqrtf(s), 1e-12f);
    }
    #pragma unroll
    for (int j = 0; j < 8; ++j)
        #pragma unroll
        for (int r = 0; r < 4; ++r)
            sc[(q * 4 + r) * 132 + j * 16 + m] = acc[j][r] * ss[r];
    // copy r0 (raw gathered ifeat) and r1 (from scratch) to output
    for (int r = 0; r < 16; ++r) {
        int row = gb + r;
        int idx = (row < BB) ? pos[row] : neg[row - BB];
        float* orow = out + (size_t)(BB + row) * 384;  // pos b -> BB+b, neg b' -> 2BB+b' == BB+row
        ((float2*)orow)[lane] = ((const float2*)(ifeat + (size_t)idx * DD))[lane];
        float2 r1v;
        r1v.x = sc[r * 132 + 2 * lane];
        r1v.y = sc[r * 132 + 2 * lane + 1];
        ((float2*)orow)[64 + lane] = r1v;
    }
    // layer 1: A-frags from scratch
    bf16x8 chi[4], clo[4];
    #pragma unroll
    for (int kk = 0; kk < 4; ++kk)
        make_afrag_hilo(sc + m * 132, kk * 32 + q * 8, &chi[kk], &clo[kk]);
    #pragma unroll
    for (int j = 0; j < 8; ++j) acc[j] = zero;
    #pragma unroll 2
    for (int j = 0; j < 8; ++j) {
        #pragma unroll
        for (int kk = 0; kk < 4; ++kk) {
            bf16x8 b = bfrag(wf, 2048 + (j * 4 + kk) * 64 + lane);
            acc[j] = mfma16(chi[kk], b, acc[j]);
            acc[j] = mfma16(clo[kk], b, acc[j]);
        }
    }
    float ss1[4] = {0.f, 0.f, 0.f, 0.f};
    #pragma unroll
    for (int j = 0; j < 8; ++j) {
        float bj = b1[j * 16 + m];
        #pragma unroll
        for (int r = 0; r < 4; ++r) {
            float x = acc[j][r] + bj;
            x = x > 0.f ? x : 0.2f * x;
            acc[j][r] = x;
            ss1[r] += x * x;
        }
    }
    #pragma unroll
    for (int r = 0; r < 4; ++r) {
        float s = ss1[r];
        s += __shfl_xor(s, 1, 64);
        s += __shfl_xor(s, 2, 64);
        s += __shfl_xor(s, 4, 64);
        s += __shfl_xor(s, 8, 64);
        ss1[r] = 1.0f / fmaxf(sqrtf(s), 1e-12f);
    }
    #pragma unroll
    for (int j = 0; j < 8; ++j)
        #pragma unroll
        for (int r = 0; r < 4; ++r)
            out[(size_t)(BB + gb + q * 4 + r) * 384 + 256 + j * 16 + m] = acc[j][r] * ss1[r];
}

extern "C" void kernel_launch(void* const* d_in, const int* in_sizes, int n_in,
                              void* d_out, int out_size, void* d_ws, size_t ws_size,
                              hipStream_t stream) {
    const int* src = (const int*)d_in[0];
    const int* dst = (const int*)d_in[1];
    const int* users = (const int*)d_in[2];
    const int* pos = (const int*)d_in[3];
    const int* neg = (const int*)d_in[4];
    const float* ufeat = (const float*)d_in[5];
    const float* ifeat = (const float*)d_in[6];
    const float* Ws0 = (const float*)d_in[7];
    const float* Wn0 = (const float*)d_in[8];
    const float* bu0 = (const float*)d_in[9];
    const float* Wi0 = (const float*)d_in[10];
    const float* bi0 = (const float*)d_in[11];
    const float* Ws1 = (const float*)d_in[12];
    const float* Wn1 = (const float*)d_in[13];
    const float* bu1 = (const float*)d_in[14];
    const float* Wi1 = (const float*)d_in[15];
    const float* bi1 = (const float*)d_in[16];
    float* out = (float*)d_out;

    char* ws = (char*)d_ws;
    int* deg = (int*)(ws + OFF_DEG);
    int* row_start = (int*)(ws + OFF_ROWSTART);
    int* cursor = (int*)(ws + OFF_CURSOR);
    int* bsum = (int*)(ws + OFF_BSUM);
    int* edge_src = (int*)(ws + OFF_EDGESRC);
    float* h1 = (float*)(ws + OFF_H1);
    u32x4* wfrag = (u32x4*)(ws + OFF_WFRAG);

    unsigned* ubf = (unsigned*)d_out;                                    // bf16 ufeat
    unsigned* hn = (unsigned*)((char*)d_out + (size_t)NU * DD * 2);      // bf16 neighbor mean
    const unsigned short* hn_us = (const unsigned short*)hn;

    hipMemsetAsync(deg, 0, NU * sizeof(int), stream);
    pack_swizzle_kernel<<<48, 256, 0, stream>>>(Ws0, Wn0, Ws1, Wn1, Wi0, Wi1, wfrag);
    deg_count_part<<<NXCD * PART_K, 256, 0, stream>>>(dst, deg);
    scan1_kernel<<<SCAN_NBLK, 256, 0, stream>>>(deg, bsum);
    scan2_kernel<<<1, 64, 0, stream>>>(bsum);
    scan3_kernel<<<SCAN_NBLK, 256, 0, stream>>>(deg, bsum, row_start, cursor);
    fill_part<<<NXCD * PART_K, 256, 0, stream>>>(src, dst, cursor, edge_src);
    cvt_kernel<<<NU * 64 / 256, 256, 0, stream>>>(ufeat, ubf);
    agg_kernel<<<(NU + 3) / 4, 256, 0, stream>>>(ubf, row_start, deg, edge_src, hn);
    user_mm_mfma<<<(USER_TILES + 3) / 4, 256, 0, stream>>>(ufeat, hn_us, wfrag, bu0, h1);
    user_l2_mfma<<<BB / 16, 256, 0, stream>>>(ufeat, h1, users, row_start, deg, edge_src,
                                              wfrag + 4096, bu1, out);
    item_mfma<<<2 * BB / 64, 256, 0, stream>>>(ifeat, pos, neg, wfrag + 8192, bi0, bi1, out);
}

// Round 4
// 505.107 us; speedup vs baseline: 1.2086x; 1.0626x over previous
//
#include <hip/hip_runtime.h>

#define NU 100000
#define NI 100000
#define NE 1600000
#define BB 16384
#define DD 128

static constexpr int SCAN_CHUNK = 2048;                       // 256 threads * 8
static constexpr int SCAN_NBLK  = (NU + SCAN_CHUNK - 1) / SCAN_CHUNK; // 49
static constexpr int USER_TILES = NU / 16;                    // 6250

static constexpr int NXCD   = 8;
static constexpr int DRANGE = NU / NXCD;                      // 12500 dsts per XCD range
static constexpr int PART_K = 128;                            // sub-blocks per range
static constexpr int DEG_BLKS = NXCD * PART_K;                // 1024
static constexpr int CVT_BLKS = NU * 64 / 256;                // 25000

// ---------- workspace layout (bytes) ----------
static constexpr size_t OFF_DEG      = 0;          // int[NU]   400000
static constexpr size_t OFF_ROWSTART = 400128;     // int[NU]
static constexpr size_t OFF_CURSOR   = 800256;     // int[NU]
static constexpr size_t OFF_BSUM     = 1200384;    // int[64]
static constexpr size_t OFF_EDGESRC  = 1200640;    // int[NE]   6400000
static constexpr size_t OFF_H1       = 7600640;    // float[NU*DD] 51200000
static constexpr size_t OFF_WFRAG    = 58800640;   // u32x4[12288] 196608 (pre-swizzled bf16 weights)
// end = 58,997,248 bytes

// d_out staging (dead before real outputs are written):
//   ubf   at d_out+0        : uint[NU*64]  25.6 MB  (ufeat in bf16 pairs)
//   hn_bf at d_out+25.6MB   : ushort[NU*128] 25.6 MB (neighbor mean, bf16)
// user_l2 writes rows 0..BB-1 (bytes 0..25.2M, ubf dead by then);
// item writes rows BB..3BB-1 (overlaps hn_bf region, dead by then).

typedef __bf16 bf16x8 __attribute__((ext_vector_type(8)));
typedef float f32x4 __attribute__((ext_vector_type(4)));
typedef unsigned int u32x4 __attribute__((ext_vector_type(4)));

union frag_u {
    u32x4 u;
    bf16x8 b;
    unsigned short us[8];
};

// ---------- helpers ----------
__device__ __forceinline__ unsigned short f2bf(float f) {
    unsigned u = __float_as_uint(f);
    u = (u + 0x7fffu + ((u >> 16) & 1u)) >> 16;  // RNE
    return (unsigned short)u;
}

__device__ __forceinline__ unsigned pack_bf16_pair(float a, float b) {
    return (unsigned)f2bf(a) | ((unsigned)f2bf(b) << 16);
}

__device__ __forceinline__ float2 unpack_bf16_pair(unsigned u) {
    float2 r;
    r.x = __uint_as_float(u << 16);
    r.y = __uint_as_float(u & 0xffff0000u);
    return r;
}

__device__ __forceinline__ f32x4 mfma16(bf16x8 a, bf16x8 b, f32x4 c) {
    return __builtin_amdgcn_mfma_f32_16x16x32_bf16(a, b, c, 0, 0, 0);
}

__device__ __forceinline__ bf16x8 bfrag(const u32x4* __restrict__ wf, int idx) {
    frag_u f;
    f.u = wf[idx];
    return f.b;
}

// A-fragment (16x16x32 layout: lane holds A[m=lane&15][kb..kb+7]) as hi/lo bf16 split.
__device__ __forceinline__ void make_afrag_hilo(const float* rowp, int kb,
                                                bf16x8* hi, bf16x8* lo) {
    float4 v0 = *(const float4*)(rowp + kb);
    float4 v1 = *(const float4*)(rowp + kb + 4);
    float vv[8] = {v0.x, v0.y, v0.z, v0.w, v1.x, v1.y, v1.z, v1.w};
    frag_u h, l;
    #pragma unroll
    for (int e = 0; e < 8; ++e) {
        unsigned short hb = f2bf(vv[e]);
        h.us[e] = hb;
        float hf = __uint_as_float(((unsigned)hb) << 16);
        l.us[e] = f2bf(vv[e] - hf);
    }
    *hi = h.b;
    *lo = l.b;
}

// ---------- fused prep: deg_count (XCD-partitioned) + ufeat->bf16 cvt ----------
// Blocks 0..1023: deg count, dst-range r = blockIdx&7 pinned to XCD r (round-robin
// dispatch) so the deg slice stays L2-resident. Blocks 1024..26023: cvt.
// The two jobs are independent; fusing them lets cvt's streaming blocks fill CU
// slots while deg blocks wait on atomics.
__global__ __launch_bounds__(256) void prep_fuse(const int* __restrict__ dst,
                                                 int* __restrict__ deg,
                                                 const float* __restrict__ uf,
                                                 unsigned* __restrict__ ubf) {
    if (blockIdx.x < DEG_BLKS) {
        int r = blockIdx.x & (NXCD - 1);
        int k = blockIdx.x >> 3;
        int lo = r * DRANGE;
        const int4* d4 = (const int4*)dst;
        int i = k * 256 + threadIdx.x;
        int stride = PART_K * 256;
        for (; i < NE / 4; i += stride) {
            int4 d = d4[i];
            if ((unsigned)(d.x - lo) < (unsigned)DRANGE) atomicAdd(&deg[d.x], 1);
            if ((unsigned)(d.y - lo) < (unsigned)DRANGE) atomicAdd(&deg[d.y], 1);
            if ((unsigned)(d.z - lo) < (unsigned)DRANGE) atomicAdd(&deg[d.z], 1);
            if ((unsigned)(d.w - lo) < (unsigned)DRANGE) atomicAdd(&deg[d.w], 1);
        }
    } else {
        int i = (blockIdx.x - DEG_BLKS) * 256 + threadIdx.x;  // NU*64 exact
        float2 v = ((const float2*)uf)[i];
        ubf[i] = pack_bf16_pair(v.x, v.y);
    }
}

__global__ __launch_bounds__(256) void scan1_kernel(const int* __restrict__ deg,
                                                    int* __restrict__ bsum) {
    __shared__ int sh[256];
    int t = threadIdx.x;
    int base = blockIdx.x * SCAN_CHUNK + t * 8;
    int s = 0;
    #pragma unroll
    for (int j = 0; j < 8; ++j) {
        int idx = base + j;
        s += (idx < NU) ? deg[idx] : 0;
    }
    sh[t] = s;
    __syncthreads();
    for (int off = 128; off > 0; off >>= 1) {
        if (t < off) sh[t] += sh[t + off];
        __syncthreads();
    }
    if (t == 0) bsum[blockIdx.x] = sh[0];
}

__global__ void scan2_kernel(int* __restrict__ bsum) {
    if (threadIdx.x == 0) {
        int acc = 0;
        for (int i = 0; i < SCAN_NBLK; ++i) {
            int v = bsum[i];
            bsum[i] = acc;
            acc += v;
        }
    }
}

__global__ __launch_bounds__(256) void scan3_kernel(const int* __restrict__ deg,
                                                    const int* __restrict__ bsum,
                                                    int* __restrict__ row_start,
                                                    int* __restrict__ cursor) {
    __shared__ int sh[256];
    int t = threadIdx.x;
    int base = blockIdx.x * SCAN_CHUNK + t * 8;
    int v[8];
    int s = 0;
    #pragma unroll
    for (int j = 0; j < 8; ++j) {
        int idx = base + j;
        v[j] = (idx < NU) ? deg[idx] : 0;
        s += v[j];
    }
    sh[t] = s;
    __syncthreads();
    for (int off = 1; off < 256; off <<= 1) {
        int val = sh[t];
        int add = (t >= off) ? sh[t - off] : 0;
        __syncthreads();
        sh[t] = val + add;
        __syncthreads();
    }
    int excl = sh[t] - s + bsum[blockIdx.x];
    #pragma unroll
    for (int j = 0; j < 8; ++j) {
        int idx = base + j;
        if (idx < NU) {
            row_start[idx] = excl;
            cursor[idx] = excl;
        }
        excl += v[j];
    }
}

__global__ __launch_bounds__(256) void fill_part(const int* __restrict__ src,
                                                 const int* __restrict__ dst,
                                                 int* __restrict__ cursor,
                                                 int* __restrict__ edge_src) {
    int r = blockIdx.x & (NXCD - 1);
    int k = blockIdx.x >> 3;
    int K = gridDim.x >> 3;
    int lo = r * DRANGE;
    const int4* d4 = (const int4*)dst;
    const int4* s4 = (const int4*)src;
    int i = k * 256 + threadIdx.x;
    int stride = K * 256;
    for (; i < NE / 4; i += stride) {
        int4 d = d4[i];
        int4 s = s4[i];
        if ((unsigned)(d.x - lo) < (unsigned)DRANGE) edge_src[atomicAdd(&cursor[d.x], 1)] = s.x;
        if ((unsigned)(d.y - lo) < (unsigned)DRANGE) edge_src[atomicAdd(&cursor[d.y], 1)] = s.y;
        if ((unsigned)(d.z - lo) < (unsigned)DRANGE) edge_src[atomicAdd(&cursor[d.z], 1)] = s.z;
        if ((unsigned)(d.w - lo) < (unsigned)DRANGE) edge_src[atomicAdd(&cursor[d.w], 1)] = s.w;
    }
}

// ---------- weight pre-swizzle: global fp32 [k][n] -> bf16 B-fragments ----------
// entry idx = matg*2048 + (j*4+kk)*64 + lane ; holds B[kb..kb+7][n] with
// n = j*16 + (lane&15), kb = kk*32 + (lane>>4)*8. 6 matrices, 12288 entries.
__global__ __launch_bounds__(256) void pack_swizzle_kernel(
    const float* __restrict__ Ws0, const float* __restrict__ Wn0,
    const float* __restrict__ Ws1, const float* __restrict__ Wn1,
    const float* __restrict__ Wi0, const float* __restrict__ Wi1,
    u32x4* __restrict__ wfrag) {
    int i = blockIdx.x * 256 + threadIdx.x;  // grid 48 -> 12288
    const float* tab[6] = {Ws0, Wn0, Ws1, Wn1, Wi0, Wi1};
    int matg = i >> 11;
    int j = (i >> 8) & 7, kk = (i >> 6) & 3, ln = i & 63;
    const float* W = tab[matg];
    int n = j * 16 + (ln & 15);
    int kb = kk * 32 + (ln >> 4) * 8;
    unsigned short u[8];
    #pragma unroll
    for (int e = 0; e < 8; ++e) u[e] = f2bf(W[(size_t)(kb + e) * DD + n]);
    u32x4 w;
    w[0] = u[0] | ((unsigned)u[1] << 16);
    w[1] = u[2] | ((unsigned)u[3] << 16);
    w[2] = u[4] | ((unsigned)u[5] << 16);
    w[3] = u[6] | ((unsigned)u[7] << 16);
    wfrag[i] = w;
}

// ---------- layer-1 aggregation: 4 edge-slots x 16 lanelets per wave ----------
// Each lane loads uint4 (16B) so one global_load_dwordx4 serves 4 edges at once
// (4x fewer vmem insts, 4x MLP vs the old 64x4B-per-edge layout). Edge indices
// prefetched coalesced (lane i -> index i) and redistributed with one shfl per
// 4-edge step. Final cross-eslot reduce: 2 shfl_xor rounds.
__global__ __launch_bounds__(256) void agg_kernel(const unsigned* __restrict__ ubf,
                                                  const int* __restrict__ row_start,
                                                  const int* __restrict__ deg,
                                                  const int* __restrict__ edge_src,
                                                  unsigned* __restrict__ hn) {
    int wid = blockIdx.x * 4 + (threadIdx.x >> 6);
    int lane = threadIdx.x & 63;
    if (wid >= NU) return;
    int st = row_start[wid];
    int dg = deg[wid];
    int lanelet = lane & 15;   // covers uints [lanelet*4 .. +3] = dims 8*lanelet..+7
    int eslot = lane >> 4;     // which of 4 concurrent edges
    float acc[8] = {0.f, 0.f, 0.f, 0.f, 0.f, 0.f, 0.f, 0.f};
    const unsigned* colp = ubf + (lanelet << 2);
    for (int base = 0; base < dg; base += 64) {
        int n = min(dg - base, 64);
        int myidx = (lane < n) ? edge_src[st + base + lane] : 0;
        int e = 0;
        #pragma unroll 2
        for (; e + 4 <= n; e += 4) {
            int s = __shfl(myidx, e + eslot, 64);
            u32x4 v = *(const u32x4*)(colp + (size_t)s * 64);
            #pragma unroll
            for (int k = 0; k < 4; ++k) {
                float2 f = unpack_bf16_pair(v[k]);
                acc[2 * k] += f.x;
                acc[2 * k + 1] += f.y;
            }
        }
        int rem = n - e;
        int s = __shfl(myidx, min(e + eslot, 63), 64);  // all lanes active for shfl
        if (eslot < rem) {
            u32x4 v = *(const u32x4*)(colp + (size_t)s * 64);
            #pragma unroll
            for (int k = 0; k < 4; ++k) {
                float2 f = unpack_bf16_pair(v[k]);
                acc[2 * k] += f.x;
                acc[2 * k + 1] += f.y;
            }
        }
    }
    #pragma unroll
    for (int k = 0; k < 8; ++k) {
        acc[k] += __shfl_xor(acc[k], 16, 64);
        acc[k] += __shfl_xor(acc[k], 32, 64);
    }
    float inv = 1.0f / fmaxf((float)dg, 1.0f);
    if (eslot == 0) {
        u32x4 o;
        o[0] = pack_bf16_pair(acc[0] * inv, acc[1] * inv);
        o[1] = pack_bf16_pair(acc[2] * inv, acc[3] * inv);
        o[2] = pack_bf16_pair(acc[4] * inv, acc[5] * inv);
        o[3] = pack_bf16_pair(acc[6] * inv, acc[7] * inv);
        *(u32x4*)(hn + (size_t)wid * 64 + (lanelet << 2)) = o;
    }
}

// ---------- user layer 1 (all rows), MFMA ----------
__global__ __launch_bounds__(256) void user_mm_mfma(
    const float* __restrict__ hself, const unsigned short* __restrict__ hn,
    const u32x4* __restrict__ wf, const float* __restrict__ bias,
    float* __restrict__ out) {
    int t = threadIdx.x;
    int lane = t & 63;
    int tile = blockIdx.x * 4 + (t >> 6);
    if (tile >= USER_TILES) return;
    int gbase = tile * 16;
    int m = lane & 15, q = lane >> 4;
    const float* selfp = hself + (size_t)(gbase + m) * DD;
    const unsigned short* neighp = hn + (size_t)(gbase + m) * DD;
    bf16x8 as_hi[4], as_lo[4], an[4];
    #pragma unroll
    for (int kk = 0; kk < 4; ++kk) {
        int kb = kk * 32 + q * 8;
        make_afrag_hilo(selfp, kb, &as_hi[kk], &as_lo[kk]);
        frag_u f;
        f.u = *(const u32x4*)(neighp + kb);  // hn already bf16: hi only
        an[kk] = f.b;
    }
    f32x4 acc[8];
    f32x4 zero = {0.f, 0.f, 0.f, 0.f};
    #pragma unroll
    for (int j = 0; j < 8; ++j) acc[j] = zero;
    #pragma unroll 2
    for (int j = 0; j < 8; ++j) {
        #pragma unroll
        for (int kk = 0; kk < 4; ++kk) {
            bf16x8 bs = bfrag(wf, (j * 4 + kk) * 64 + lane);
            acc[j] = mfma16(as_hi[kk], bs, acc[j]);
            acc[j] = mfma16(as_lo[kk], bs, acc[j]);
            bf16x8 bn = bfrag(wf, 2048 + (j * 4 + kk) * 64 + lane);
            acc[j] = mfma16(an[kk], bn, acc[j]);
        }
    }
    float ss[4] = {0.f, 0.f, 0.f, 0.f};
    #pragma unroll
    for (int j = 0; j < 8; ++j) {
        float bj = bias[j * 16 + m];
        #pragma unroll
        for (int r = 0; r < 4; ++r) {
            float x = acc[j][r] + bj;
            x = x > 0.f ? x : 0.2f * x;
            acc[j][r] = x;
            ss[r] += x * x;
        }
    }
    #pragma unroll
    for (int r = 0; r < 4; ++r) {
        float s = ss[r];
        s += __shfl_xor(s, 1, 64);
        s += __shfl_xor(s, 2, 64);
        s += __shfl_xor(s, 4, 64);
        s += __shfl_xor(s, 8, 64);
        ss[r] = 1.0f / fmaxf(sqrtf(s), 1e-12f);
    }
    #pragma unroll
    for (int j = 0; j < 8; ++j)
        #pragma unroll
        for (int r = 0; r < 4; ++r)
            out[(size_t)(gbase + q * 4 + r) * DD + j * 16 + m] = acc[j][r] * ss[r];
}

// ---------- fused tail: user_l2 (blocks 0..1023) + item (blocks 1024..1535) ----
// Independent work; fusing lets item's compute-heavy blocks fill CU slots while
// user_l2's gather waits on memory.
__global__ __launch_bounds__(256) void tail_fuse(
    const float* __restrict__ ufeat, const float* __restrict__ h1,
    const int* __restrict__ users, const int* __restrict__ row_start,
    const int* __restrict__ deg, const int* __restrict__ edge_src,
    const float* __restrict__ ifeat, const int* __restrict__ pos,
    const int* __restrict__ neg, const u32x4* __restrict__ wf_u,
    const u32x4* __restrict__ wf_i, const float* __restrict__ bu1,
    const float* __restrict__ bi0, const float* __restrict__ bi1,
    float* __restrict__ out) {
    __shared__ float scratch[4][16 * 132];
    int t = threadIdx.x;
    int lane = t & 63, wave = t >> 6;
    int m = lane & 15, q = lane >> 4;
    f32x4 zero = {0.f, 0.f, 0.f, 0.f};

    if (blockIdx.x < 1024) {
        // ================= user layer 2 =================
        int gb = blockIdx.x * 16;
        float* sc = scratch[0];
        // phase 1: each wave aggregates 4 rows of h1 into scratch + copies cols 0..255
        #pragma unroll
        for (int rr = 0; rr < 4; ++rr) {
            int r = wave * 4 + rr;
            int u = users[gb + r];
            int st = row_start[u], dg = deg[u], en = st + dg;
            float ax = 0.f, ay = 0.f;
            int e = st;
            for (; e + 4 <= en; e += 4) {
                int s0 = edge_src[e], s1 = edge_src[e + 1];
                int s2 = edge_src[e + 2], s3 = edge_src[e + 3];
                float2 v0 = ((const float2*)(h1 + (size_t)s0 * DD))[lane];
                float2 v1 = ((const float2*)(h1 + (size_t)s1 * DD))[lane];
                float2 v2 = ((const float2*)(h1 + (size_t)s2 * DD))[lane];
                float2 v3 = ((const float2*)(h1 + (size_t)s3 * DD))[lane];
                ax += v0.x + v1.x + v2.x + v3.x;
                ay += v0.y + v1.y + v2.y + v3.y;
            }
            for (; e < en; ++e) {
                float2 v = ((const float2*)(h1 + (size_t)edge_src[e] * DD))[lane];
                ax += v.x;
                ay += v.y;
            }
            float inv = 1.0f / fmaxf((float)dg, 1.0f);
            sc[r * 132 + 2 * lane] = ax * inv;
            sc[r * 132 + 2 * lane + 1] = ay * inv;
            float* orow = out + (size_t)(gb + r) * 384;
            ((float2*)orow)[lane] = ((const float2*)(ufeat + (size_t)u * DD))[lane];
            ((float2*)orow)[64 + lane] = ((const float2*)(h1 + (size_t)u * DD))[lane];
        }
        __syncthreads();
        if (wave != 0) return;
        // phase 2: MFMA (wave 0 only)
        int um = users[gb + m];
        const float* selfp = h1 + (size_t)um * DD;
        bf16x8 sh[4], sl[4], nh[4], nl[4];
        #pragma unroll
        for (int kk = 0; kk < 4; ++kk) {
            int kb = kk * 32 + q * 8;
            make_afrag_hilo(selfp, kb, &sh[kk], &sl[kk]);
            make_afrag_hilo(sc + m * 132, kb, &nh[kk], &nl[kk]);
        }
        f32x4 acc[8];
        #pragma unroll
        for (int j = 0; j < 8; ++j) acc[j] = zero;
        #pragma unroll 2
        for (int j = 0; j < 8; ++j) {
            #pragma unroll
            for (int kk = 0; kk < 4; ++kk) {
                bf16x8 bs = bfrag(wf_u, (j * 4 + kk) * 64 + lane);
                acc[j] = mfma16(sh[kk], bs, acc[j]);
                acc[j] = mfma16(sl[kk], bs, acc[j]);
                bf16x8 bn = bfrag(wf_u, 2048 + (j * 4 + kk) * 64 + lane);
                acc[j] = mfma16(nh[kk], bn, acc[j]);
                acc[j] = mfma16(nl[kk], bn, acc[j]);
            }
        }
        float ss[4] = {0.f, 0.f, 0.f, 0.f};
        #pragma unroll
        for (int j = 0; j < 8; ++j) {
            float bj = bu1[j * 16 + m];
            #pragma unroll
            for (int r = 0; r < 4; ++r) {
                float x = acc[j][r] + bj;
                x = x > 0.f ? x : 0.2f * x;
                acc[j][r] = x;
                ss[r] += x * x;
            }
        }
        #pragma unroll
        for (int r = 0; r < 4; ++r) {
            float s = ss[r];
            s += __shfl_xor(s, 1, 64);
            s += __shfl_xor(s, 2, 64);
            s += __shfl_xor(s, 4, 64);
            s += __shfl_xor(s, 8, 64);
            ss[r] = 1.0f / fmaxf(sqrtf(s), 1e-12f);
        }
        #pragma unroll
        for (int j = 0; j < 8; ++j)
            #pragma unroll
            for (int r = 0; r < 4; ++r)
                out[(size_t)(gb + q * 4 + r) * 384 + 256 + j * 16 + m] = acc[j][r] * ss[r];
        return;
    }

    // ================= item side =================
    int tile = (blockIdx.x - 1024) * 4 + wave;  // 2048 tiles exact
    int gb = tile * 16;
    float* sc = scratch[wave];
    int rowm = gb + m;
    int idxm = (rowm < BB) ? pos[rowm] : neg[rowm - BB];
    const float* rowp = ifeat + (size_t)idxm * DD;
    bf16x8 ahi[4], alo[4];
    #pragma unroll
    for (int kk = 0; kk < 4; ++kk)
        make_afrag_hilo(rowp, kk * 32 + q * 8, &ahi[kk], &alo[kk]);
    f32x4 acc[8];
    #pragma unroll
    for (int j = 0; j < 8; ++j) acc[j] = zero;
    #pragma unroll 2
    for (int j = 0; j < 8; ++j) {
        #pragma unroll
        for (int kk = 0; kk < 4; ++kk) {
            bf16x8 b = bfrag(wf_i, (j * 4 + kk) * 64 + lane);
            acc[j] = mfma16(ahi[kk], b, acc[j]);
            acc[j] = mfma16(alo[kk], b, acc[j]);
        }
    }
    // epilogue 0 -> r1 in scratch
    float ss[4] = {0.f, 0.f, 0.f, 0.f};
    #pragma unroll
    for (int j = 0; j < 8; ++j) {
        float bj = bi0[j * 16 + m];
        #pragma unroll
        for (int r = 0; r < 4; ++r) {
            float x = acc[j][r] + bj;
            x = x > 0.f ? x : 0.2f * x;
            acc[j][r] = x;
            ss[r] += x * x;
        }
    }
    #pragma unroll
    for (int r = 0; r < 4; ++r) {
        float s = ss[r];
        s += __shfl_xor(s, 1, 64);
        s += __shfl_xor(s, 2, 64);
        s += __shfl_xor(s, 4, 64);
        s += __shfl_xor(s, 8, 64);
        ss[r] = 1.0f / fmaxf(sqrtf(s), 1e-12f);
    }
    #pragma unroll
    for (int j = 0; j < 8; ++j)
        #pragma unroll
        for (int r = 0; r < 4; ++r)
            sc[(q * 4 + r) * 132 + j * 16 + m] = acc[j][r] * ss[r];
    // copy r0 (raw gathered ifeat) and r1 (from scratch) to output
    for (int r = 0; r < 16; ++r) {
        int row = gb + r;
        int idx = (row < BB) ? pos[row] : neg[row - BB];
        float* orow = out + (size_t)(BB + row) * 384;  // pos b -> BB+b, neg b' -> 2BB+b' == BB+row
        ((float2*)orow)[lane] = ((const float2*)(ifeat + (size_t)idx * DD))[lane];
        float2 r1v;
        r1v.x = sc[r * 132 + 2 * lane];
        r1v.y = sc[r * 132 + 2 * lane + 1];
        ((float2*)orow)[64 + lane] = r1v;
    }
    // layer 1: A-frags from scratch
    bf16x8 chi[4], clo[4];
    #pragma unroll
    for (int kk = 0; kk < 4; ++kk)
        make_afrag_hilo(sc + m * 132, kk * 32 + q * 8, &chi[kk], &clo[kk]);
    #pragma unroll
    for (int j = 0; j < 8; ++j) acc[j] = zero;
    #pragma unroll 2
    for (int j = 0; j < 8; ++j) {
        #pragma unroll
        for (int kk = 0; kk < 4; ++kk) {
            bf16x8 b = bfrag(wf_i, 2048 + (j * 4 + kk) * 64 + lane);
            acc[j] = mfma16(chi[kk], b, acc[j]);
            acc[j] = mfma16(clo[kk], b, acc[j]);
        }
    }
    float ss1[4] = {0.f, 0.f, 0.f, 0.f};
    #pragma unroll
    for (int j = 0; j < 8; ++j) {
        float bj = bi1[j * 16 + m];
        #pragma unroll
        for (int r = 0; r < 4; ++r) {
            float x = acc[j][r] + bj;
            x = x > 0.f ? x : 0.2f * x;
            acc[j][r] = x;
            ss1[r] += x * x;
        }
    }
    #pragma unroll
    for (int r = 0; r < 4; ++r) {
        float s = ss1[r];
        s += __shfl_xor(s, 1, 64);
        s += __shfl_xor(s, 2, 64);
        s += __shfl_xor(s, 4, 64);
        s += __shfl_xor(s, 8, 64);
        ss1[r] = 1.0f / fmaxf(sqrtf(s), 1e-12f);
    }
    #pragma unroll
    for (int j = 0; j < 8; ++j)
        #pragma unroll
        for (int r = 0; r < 4; ++r)
            out[(size_t)(BB + gb + q * 4 + r) * 384 + 256 + j * 16 + m] = acc[j][r] * ss1[r];
}

extern "C" void kernel_launch(void* const* d_in, const int* in_sizes, int n_in,
                              void* d_out, int out_size, void* d_ws, size_t ws_size,
                              hipStream_t stream) {
    const int* src = (const int*)d_in[0];
    const int* dst = (const int*)d_in[1];
    const int* users = (const int*)d_in[2];
    const int* pos = (const int*)d_in[3];
    const int* neg = (const int*)d_in[4];
    const float* ufeat = (const float*)d_in[5];
    const float* ifeat = (const float*)d_in[6];
    const float* Ws0 = (const float*)d_in[7];
    const float* Wn0 = (const float*)d_in[8];
    const float* bu0 = (const float*)d_in[9];
    const float* Wi0 = (const float*)d_in[10];
    const float* bi0 = (const float*)d_in[11];
    const float* Ws1 = (const float*)d_in[12];
    const float* Wn1 = (const float*)d_in[13];
    const float* bu1 = (const float*)d_in[14];
    const float* Wi1 = (const float*)d_in[15];
    const float* bi1 = (const float*)d_in[16];
    float* out = (float*)d_out;

    char* ws = (char*)d_ws;
    int* deg = (int*)(ws + OFF_DEG);
    int* row_start = (int*)(ws + OFF_ROWSTART);
    int* cursor = (int*)(ws + OFF_CURSOR);
    int* bsum = (int*)(ws + OFF_BSUM);
    int* edge_src = (int*)(ws + OFF_EDGESRC);
    float* h1 = (float*)(ws + OFF_H1);
    u32x4* wfrag = (u32x4*)(ws + OFF_WFRAG);

    unsigned* ubf = (unsigned*)d_out;                                    // bf16 ufeat
    unsigned* hn = (unsigned*)((char*)d_out + (size_t)NU * DD * 2);      // bf16 neighbor mean
    const unsigned short* hn_us = (const unsigned short*)hn;

    hipMemsetAsync(deg, 0, NU * sizeof(int), stream);
    prep_fuse<<<DEG_BLKS + CVT_BLKS, 256, 0, stream>>>(dst, deg, ufeat, ubf);
    pack_swizzle_kernel<<<48, 256, 0, stream>>>(Ws0, Wn0, Ws1, Wn1, Wi0, Wi1, wfrag);
    scan1_kernel<<<SCAN_NBLK, 256, 0, stream>>>(deg, bsum);
    scan2_kernel<<<1, 64, 0, stream>>>(bsum);
    scan3_kernel<<<SCAN_NBLK, 256, 0, stream>>>(deg, bsum, row_start, cursor);
    fill_part<<<NXCD * PART_K, 256, 0, stream>>>(src, dst, cursor, edge_src);
    agg_kernel<<<(NU + 3) / 4, 256, 0, stream>>>(ubf, row_start, deg, edge_src, hn);
    user_mm_mfma<<<(USER_TILES + 3) / 4, 256, 0, stream>>>(ufeat, hn_us, wfrag, bu0, h1);
    tail_fuse<<<1024 + 512, 256, 0, stream>>>(ufeat, h1, users, row_start, deg, edge_src,
                                              ifeat, pos, neg, wfrag + 4096, wfrag + 8192,
                                              bu1, bi0, bi1, out);
}

// Round 5
// 453.255 us; speedup vs baseline: 1.3468x; 1.1144x over previous
//
#include <hip/hip_runtime.h>

#define NU 100000
#define NI 100000
#define NE 1600000
#define BB 16384
#define DD 128

static constexpr int SCAN_CHUNK = 2048;                       // 256 threads * 8
static constexpr int SCAN_NBLK  = (NU + SCAN_CHUNK - 1) / SCAN_CHUNK; // 49
static constexpr int USER_TILES = NU / 16;                    // 6250

static constexpr int NXCD   = 8;
static constexpr int DRANGE = NU / NXCD;                      // 12500 dsts per range
static constexpr int K_CH   = 32;                             // edge chunks
static constexpr int CHUNK4 = NE / 4 / K_CH;                  // 12500 int4 per chunk
static constexpr int HIST_BLKS = NXCD * K_CH;                 // 256
static constexpr int PACK_BLKS = 48;
static constexpr int CVT_UNIT  = 2048;                        // uint2 outputs per block
static constexpr int CVT_TOT   = NU * 32;                     // 3.2M uint2 (= NU*64 uints)
static constexpr int CVT_BLKS  = (CVT_TOT + CVT_UNIT - 1) / CVT_UNIT; // 1563

// ---------- workspace layout (bytes) ----------
static constexpr size_t OFF_DEG      = 0;          // int[NU]   400000
static constexpr size_t OFF_ROWSTART = 400128;     // int[NU]
static constexpr size_t OFF_CURSOR   = 800256;     // (unused now)
static constexpr size_t OFF_BSUM     = 1200384;    // int[64]
static constexpr size_t OFF_EDGESRC  = 1200640;    // int[NE]   6400000
static constexpr size_t OFF_H1       = 7600640;    // float[NU*DD] 51200000
static constexpr size_t OFF_WFRAG    = 58800640;   // u32x4[12288] 196608 (pre-swizzled bf16 weights)
// end = 58,997,248 bytes

// d_out staging (dead before real outputs are written):
//   ubf  at d_out+0          : uint[NU*64]   25.6 MB (ufeat bf16 pairs; dead after agg)
//   hn   at d_out+25.6MB     : ushort[NU*128] 25.6 MB (neighbor mean; dead after user_mm)
//   hist at d_out+51.2MB     : int[8*32*12500] 12.8 MB (chunk histograms / cursor bases;
//                              dead after fill2, overwritten only by tail_fuse)

typedef __bf16 bf16x8 __attribute__((ext_vector_type(8)));
typedef float f32x4 __attribute__((ext_vector_type(4)));
typedef unsigned int u32x4 __attribute__((ext_vector_type(4)));

union frag_u {
    u32x4 u;
    bf16x8 b;
    unsigned short us[8];
};

// ---------- helpers ----------
__device__ __forceinline__ unsigned short f2bf(float f) {
    unsigned u = __float_as_uint(f);
    u = (u + 0x7fffu + ((u >> 16) & 1u)) >> 16;  // RNE
    return (unsigned short)u;
}

__device__ __forceinline__ unsigned pack_bf16_pair(float a, float b) {
    return (unsigned)f2bf(a) | ((unsigned)f2bf(b) << 16);
}

__device__ __forceinline__ float2 unpack_bf16_pair(unsigned u) {
    float2 r;
    r.x = __uint_as_float(u << 16);
    r.y = __uint_as_float(u & 0xffff0000u);
    return r;
}

__device__ __forceinline__ f32x4 mfma16(bf16x8 a, bf16x8 b, f32x4 c) {
    return __builtin_amdgcn_mfma_f32_16x16x32_bf16(a, b, c, 0, 0, 0);
}

__device__ __forceinline__ bf16x8 bfrag(const u32x4* __restrict__ wf, int idx) {
    frag_u f;
    f.u = wf[idx];
    return f.b;
}

// A-fragment (16x16x32 layout: lane holds A[m=lane&15][kb..kb+7]) as hi/lo bf16 split.
__device__ __forceinline__ void make_afrag_hilo(const float* rowp, int kb,
                                                bf16x8* hi, bf16x8* lo) {
    float4 v0 = *(const float4*)(rowp + kb);
    float4 v1 = *(const float4*)(rowp + kb + 4);
    float vv[8] = {v0.x, v0.y, v0.z, v0.w, v1.x, v1.y, v1.z, v1.w};
    frag_u h, l;
    #pragma unroll
    for (int e = 0; e < 8; ++e) {
        unsigned short hb = f2bf(vv[e]);
        h.us[e] = hb;
        float hf = __uint_as_float(((unsigned)hb) << 16);
        l.us[e] = f2bf(vv[e] - hf);
    }
    *hi = h.b;
    *lo = l.b;
}

// ---------- mega prep: LDS histograms + weight pack + ufeat cvt ----------
// Blocks 0..255        : hist block (k = bid>>3, r = bid&7). Private LDS histogram
//                        of chunk k filtered to dst-range r; flushed with plain
//                        coalesced stores -> hist[r][k][*]. ZERO global atomics.
// Blocks 256..303      : weight pre-swizzle (fp32 [k][n] -> bf16 B-fragments).
// Blocks 304..304+1562 : ufeat fp32 -> packed bf16 pairs (float4 loads, uint2 stores).
__global__ __launch_bounds__(256) void mega_prep(
    const int* __restrict__ dst, int* __restrict__ hist,
    const float* __restrict__ uf, unsigned* __restrict__ ubf,
    const float* __restrict__ Ws0, const float* __restrict__ Wn0,
    const float* __restrict__ Ws1, const float* __restrict__ Wn1,
    const float* __restrict__ Wi0, const float* __restrict__ Wi1,
    u32x4* __restrict__ wfrag) {
    __shared__ int h[DRANGE];  // 50 KB
    int t = threadIdx.x;
    if (blockIdx.x < HIST_BLKS) {
        int r = blockIdx.x & (NXCD - 1);
        int k = blockIdx.x >> 3;
        for (int j = t; j < DRANGE; j += 256) h[j] = 0;
        __syncthreads();
        int lo = r * DRANGE;
        const int4* d4 = (const int4*)dst + (size_t)k * CHUNK4;
        for (int i = t; i < CHUNK4; i += 256) {
            int4 d = d4[i];
            if ((unsigned)(d.x - lo) < (unsigned)DRANGE) atomicAdd(&h[d.x - lo], 1);
            if ((unsigned)(d.y - lo) < (unsigned)DRANGE) atomicAdd(&h[d.y - lo], 1);
            if ((unsigned)(d.z - lo) < (unsigned)DRANGE) atomicAdd(&h[d.z - lo], 1);
            if ((unsigned)(d.w - lo) < (unsigned)DRANGE) atomicAdd(&h[d.w - lo], 1);
        }
        __syncthreads();
        int* hb = hist + (size_t)(r * K_CH + k) * DRANGE;
        for (int j = t; j < DRANGE; j += 256) hb[j] = h[j];
    } else if (blockIdx.x < HIST_BLKS + PACK_BLKS) {
        int i = (blockIdx.x - HIST_BLKS) * 256 + t;  // 12288 exact
        const float* tab[6] = {Ws0, Wn0, Ws1, Wn1, Wi0, Wi1};
        int matg = i >> 11;
        int j = (i >> 8) & 7, kk = (i >> 6) & 3, ln = i & 63;
        const float* W = tab[matg];
        int n = j * 16 + (ln & 15);
        int kb = kk * 32 + (ln >> 4) * 8;
        unsigned short u[8];
        #pragma unroll
        for (int e = 0; e < 8; ++e) u[e] = f2bf(W[(size_t)(kb + e) * DD + n]);
        u32x4 w;
        w[0] = u[0] | ((unsigned)u[1] << 16);
        w[1] = u[2] | ((unsigned)u[3] << 16);
        w[2] = u[4] | ((unsigned)u[5] << 16);
        w[3] = u[6] | ((unsigned)u[7] << 16);
        wfrag[i] = w;
    } else {
        int bid2 = blockIdx.x - HIST_BLKS - PACK_BLKS;
        const float4* uf4 = (const float4*)uf;
        uint2* ub2 = (uint2*)ubf;
        #pragma unroll
        for (int it = 0; it < 8; ++it) {
            int idx = bid2 * CVT_UNIT + it * 256 + t;
            if (idx < CVT_TOT) {
                float4 v = uf4[idx];
                uint2 o;
                o.x = pack_bf16_pair(v.x, v.y);
                o.y = pack_bf16_pair(v.z, v.w);
                ub2[idx] = o;
            }
        }
    }
}

// ---------- deg[d] = sum_k hist[r][k][j] ----------
__global__ __launch_bounds__(256) void deg_reduce(const int* __restrict__ hist,
                                                  int* __restrict__ deg) {
    int d = blockIdx.x * 256 + threadIdx.x;
    if (d >= NU) return;
    int r = d / DRANGE, j = d - r * DRANGE;
    const int* hb = hist + (size_t)r * K_CH * DRANGE + j;
    int s = 0;
    #pragma unroll
    for (int k = 0; k < K_CH; ++k) s += hb[(size_t)k * DRANGE];
    deg[d] = s;
}

__global__ __launch_bounds__(256) void scan1_kernel(const int* __restrict__ deg,
                                                    int* __restrict__ bsum) {
    __shared__ int sh[256];
    int t = threadIdx.x;
    int base = blockIdx.x * SCAN_CHUNK + t * 8;
    int s = 0;
    #pragma unroll
    for (int j = 0; j < 8; ++j) {
        int idx = base + j;
        s += (idx < NU) ? deg[idx] : 0;
    }
    sh[t] = s;
    __syncthreads();
    for (int off = 128; off > 0; off >>= 1) {
        if (t < off) sh[t] += sh[t + off];
        __syncthreads();
    }
    if (t == 0) bsum[blockIdx.x] = sh[0];
}

__global__ void scan2_kernel(int* __restrict__ bsum) {
    if (threadIdx.x == 0) {
        int acc = 0;
        for (int i = 0; i < SCAN_NBLK; ++i) {
            int v = bsum[i];
            bsum[i] = acc;
            acc += v;
        }
    }
}

__global__ __launch_bounds__(256) void scan3_kernel(const int* __restrict__ deg,
                                                    const int* __restrict__ bsum,
                                                    int* __restrict__ row_start) {
    __shared__ int sh[256];
    int t = threadIdx.x;
    int base = blockIdx.x * SCAN_CHUNK + t * 8;
    int v[8];
    int s = 0;
    #pragma unroll
    for (int j = 0; j < 8; ++j) {
        int idx = base + j;
        v[j] = (idx < NU) ? deg[idx] : 0;
        s += v[j];
    }
    sh[t] = s;
    __syncthreads();
    for (int off = 1; off < 256; off <<= 1) {
        int val = sh[t];
        int add = (t >= off) ? sh[t - off] : 0;
        __syncthreads();
        sh[t] = val + add;
        __syncthreads();
    }
    int excl = sh[t] - s + bsum[blockIdx.x];
    #pragma unroll
    for (int j = 0; j < 8; ++j) {
        int idx = base + j;
        if (idx < NU) row_start[idx] = excl;
        excl += v[j];
    }
}

// ---------- hist -> per-(r,k) cursor bases (in place) ----------
// base[r][k][j] = row_start[d] + sum_{k'<k} hist[r][k'][j]
__global__ __launch_bounds__(256) void base_kernel(const int* __restrict__ row_start,
                                                   int* __restrict__ hist) {
    int d = blockIdx.x * 256 + threadIdx.x;
    if (d >= NU) return;
    int r = d / DRANGE, j = d - r * DRANGE;
    int* hb = hist + (size_t)r * K_CH * DRANGE + j;
    int acc = row_start[d];
    #pragma unroll
    for (int k = 0; k < K_CH; ++k) {
        int c = hb[(size_t)k * DRANGE];
        hb[(size_t)k * DRANGE] = acc;
        acc += c;
    }
}

// ---------- CSR fill: LDS cursors only, zero global atomics ----------
// Block (k,r): load base slice -> LDS, scan chunk k, place matching edges at
// LDS-atomic cursor slots. r = blockIdx&7 -> XCD r so the scattered edge_src
// stores assemble full lines in one XCD's L2 (no partial-line write amp).
__global__ __launch_bounds__(256) void fill2(const int* __restrict__ src,
                                             const int* __restrict__ dst,
                                             const int* __restrict__ base,
                                             int* __restrict__ edge_src) {
    __shared__ int cur[DRANGE];  // 50 KB
    int r = blockIdx.x & (NXCD - 1);
    int k = blockIdx.x >> 3;
    int t = threadIdx.x;
    const int* bb = base + (size_t)(r * K_CH + k) * DRANGE;
    for (int j = t; j < DRANGE; j += 256) cur[j] = bb[j];
    __syncthreads();
    int lo = r * DRANGE;
    const int4* d4 = (const int4*)dst + (size_t)k * CHUNK4;
    const int4* s4 = (const int4*)src + (size_t)k * CHUNK4;
    for (int i = t; i < CHUNK4; i += 256) {
        int4 d = d4[i];
        int4 s = s4[i];
        if ((unsigned)(d.x - lo) < (unsigned)DRANGE) edge_src[atomicAdd(&cur[d.x - lo], 1)] = s.x;
        if ((unsigned)(d.y - lo) < (unsigned)DRANGE) edge_src[atomicAdd(&cur[d.y - lo], 1)] = s.y;
        if ((unsigned)(d.z - lo) < (unsigned)DRANGE) edge_src[atomicAdd(&cur[d.z - lo], 1)] = s.z;
        if ((unsigned)(d.w - lo) < (unsigned)DRANGE) edge_src[atomicAdd(&cur[d.w - lo], 1)] = s.w;
    }
}

// ---------- layer-1 aggregation: 4 edge-slots x 16 lanelets per wave ----------
__global__ __launch_bounds__(256) void agg_kernel(const unsigned* __restrict__ ubf,
                                                  const int* __restrict__ row_start,
                                                  const int* __restrict__ deg,
                                                  const int* __restrict__ edge_src,
                                                  unsigned* __restrict__ hn) {
    int wid = blockIdx.x * 4 + (threadIdx.x >> 6);
    int lane = threadIdx.x & 63;
    if (wid >= NU) return;
    int st = row_start[wid];
    int dg = deg[wid];
    int lanelet = lane & 15;   // covers uints [lanelet*4 .. +3] = dims 8*lanelet..+7
    int eslot = lane >> 4;     // which of 4 concurrent edges
    float acc[8] = {0.f, 0.f, 0.f, 0.f, 0.f, 0.f, 0.f, 0.f};
    const unsigned* colp = ubf + (lanelet << 2);
    for (int base = 0; base < dg; base += 64) {
        int n = min(dg - base, 64);
        int myidx = (lane < n) ? edge_src[st + base + lane] : 0;
        int e = 0;
        #pragma unroll 2
        for (; e + 4 <= n; e += 4) {
            int s = __shfl(myidx, e + eslot, 64);
            u32x4 v = *(const u32x4*)(colp + (size_t)s * 64);
            #pragma unroll
            for (int k = 0; k < 4; ++k) {
                float2 f = unpack_bf16_pair(v[k]);
                acc[2 * k] += f.x;
                acc[2 * k + 1] += f.y;
            }
        }
        int rem = n - e;
        int s = __shfl(myidx, min(e + eslot, 63), 64);  // all lanes active for shfl
        if (eslot < rem) {
            u32x4 v = *(const u32x4*)(colp + (size_t)s * 64);
            #pragma unroll
            for (int k = 0; k < 4; ++k) {
                float2 f = unpack_bf16_pair(v[k]);
                acc[2 * k] += f.x;
                acc[2 * k + 1] += f.y;
            }
        }
    }
    #pragma unroll
    for (int k = 0; k < 8; ++k) {
        acc[k] += __shfl_xor(acc[k], 16, 64);
        acc[k] += __shfl_xor(acc[k], 32, 64);
    }
    float inv = 1.0f / fmaxf((float)dg, 1.0f);
    if (eslot == 0) {
        u32x4 o;
        o[0] = pack_bf16_pair(acc[0] * inv, acc[1] * inv);
        o[1] = pack_bf16_pair(acc[2] * inv, acc[3] * inv);
        o[2] = pack_bf16_pair(acc[4] * inv, acc[5] * inv);
        o[3] = pack_bf16_pair(acc[6] * inv, acc[7] * inv);
        *(u32x4*)(hn + (size_t)wid * 64 + (lanelet << 2)) = o;
    }
}

// ---------- user layer 1 (all rows), MFMA ----------
__global__ __launch_bounds__(256) void user_mm_mfma(
    const float* __restrict__ hself, const unsigned short* __restrict__ hn,
    const u32x4* __restrict__ wf, const float* __restrict__ bias,
    float* __restrict__ out) {
    int t = threadIdx.x;
    int lane = t & 63;
    int tile = blockIdx.x * 4 + (t >> 6);
    if (tile >= USER_TILES) return;
    int gbase = tile * 16;
    int m = lane & 15, q = lane >> 4;
    const float* selfp = hself + (size_t)(gbase + m) * DD;
    const unsigned short* neighp = hn + (size_t)(gbase + m) * DD;
    bf16x8 as_hi[4], as_lo[4], an[4];
    #pragma unroll
    for (int kk = 0; kk < 4; ++kk) {
        int kb = kk * 32 + q * 8;
        make_afrag_hilo(selfp, kb, &as_hi[kk], &as_lo[kk]);
        frag_u f;
        f.u = *(const u32x4*)(neighp + kb);  // hn already bf16: hi only
        an[kk] = f.b;
    }
    f32x4 acc[8];
    f32x4 zero = {0.f, 0.f, 0.f, 0.f};
    #pragma unroll
    for (int j = 0; j < 8; ++j) acc[j] = zero;
    #pragma unroll 2
    for (int j = 0; j < 8; ++j) {
        #pragma unroll
        for (int kk = 0; kk < 4; ++kk) {
            bf16x8 bs = bfrag(wf, (j * 4 + kk) * 64 + lane);
            acc[j] = mfma16(as_hi[kk], bs, acc[j]);
            acc[j] = mfma16(as_lo[kk], bs, acc[j]);
            bf16x8 bn = bfrag(wf, 2048 + (j * 4 + kk) * 64 + lane);
            acc[j] = mfma16(an[kk], bn, acc[j]);
        }
    }
    float ss[4] = {0.f, 0.f, 0.f, 0.f};
    #pragma unroll
    for (int j = 0; j < 8; ++j) {
        float bj = bias[j * 16 + m];
        #pragma unroll
        for (int r = 0; r < 4; ++r) {
            float x = acc[j][r] + bj;
            x = x > 0.f ? x : 0.2f * x;
            acc[j][r] = x;
            ss[r] += x * x;
        }
    }
    #pragma unroll
    for (int r = 0; r < 4; ++r) {
        float s = ss[r];
        s += __shfl_xor(s, 1, 64);
        s += __shfl_xor(s, 2, 64);
        s += __shfl_xor(s, 4, 64);
        s += __shfl_xor(s, 8, 64);
        ss[r] = 1.0f / fmaxf(sqrtf(s), 1e-12f);
    }
    #pragma unroll
    for (int j = 0; j < 8; ++j)
        #pragma unroll
        for (int r = 0; r < 4; ++r)
            out[(size_t)(gbase + q * 4 + r) * DD + j * 16 + m] = acc[j][r] * ss[r];
}

// ---------- fused tail: user_l2 (blocks 0..1023) + item (blocks 1024..1535) ----
__global__ __launch_bounds__(256) void tail_fuse(
    const float* __restrict__ ufeat, const float* __restrict__ h1,
    const int* __restrict__ users, const int* __restrict__ row_start,
    const int* __restrict__ deg, const int* __restrict__ edge_src,
    const float* __restrict__ ifeat, const int* __restrict__ pos,
    const int* __restrict__ neg, const u32x4* __restrict__ wf_u,
    const u32x4* __restrict__ wf_i, const float* __restrict__ bu1,
    const float* __restrict__ bi0, const float* __restrict__ bi1,
    float* __restrict__ out) {
    __shared__ float scratch[4][16 * 132];
    int t = threadIdx.x;
    int lane = t & 63, wave = t >> 6;
    int m = lane & 15, q = lane >> 4;
    f32x4 zero = {0.f, 0.f, 0.f, 0.f};

    if (blockIdx.x < 1024) {
        // ================= user layer 2 =================
        int gb = blockIdx.x * 16;
        float* sc = scratch[0];
        int L = lane & 31;      // lanelet: 16B = 4 floats of the row
        int eslot = lane >> 5;  // 2 concurrent edges
        const float* hl = h1 + 4 * L;
        // phase 1: each wave aggregates 4 rows of h1 into scratch + copies cols 0..255
        #pragma unroll
        for (int rr = 0; rr < 4; ++rr) {
            int r = wave * 4 + rr;
            int u = users[gb + r];
            int st = row_start[u], dg = deg[u], en = st + dg;
            float ax = 0.f, ay = 0.f, az = 0.f, aw = 0.f;
            int e = st;
            for (; e + 4 <= en; e += 4) {
                int s0 = edge_src[e], s1 = edge_src[e + 1];
                int s2 = edge_src[e + 2], s3 = edge_src[e + 3];
                int sA = eslot ? s1 : s0;
                int sB = eslot ? s3 : s2;
                float4 vA = *(const float4*)(hl + (size_t)sA * DD);
                float4 vB = *(const float4*)(hl + (size_t)sB * DD);
                ax += vA.x + vB.x;
                ay += vA.y + vB.y;
                az += vA.z + vB.z;
                aw += vA.w + vB.w;
            }
            if (e + 2 <= en) {
                int s0 = edge_src[e], s1 = edge_src[e + 1];
                int sA = eslot ? s1 : s0;
                float4 vA = *(const float4*)(hl + (size_t)sA * DD);
                ax += vA.x;
                ay += vA.y;
                az += vA.z;
                aw += vA.w;
                e += 2;
            }
            if (e < en) {
                int s0 = edge_src[e];
                if (eslot == 0) {
                    float4 vA = *(const float4*)(hl + (size_t)s0 * DD);
                    ax += vA.x;
                    ay += vA.y;
                    az += vA.z;
                    aw += vA.w;
                }
            }
            ax += __shfl_xor(ax, 32, 64);
            ay += __shfl_xor(ay, 32, 64);
            az += __shfl_xor(az, 32, 64);
            aw += __shfl_xor(aw, 32, 64);
            float inv = 1.0f / fmaxf((float)dg, 1.0f);
            if (eslot == 0) {
                float4 o = {ax * inv, ay * inv, az * inv, aw * inv};
                *(float4*)(sc + r * 132 + 4 * L) = o;
            }
            float* orow = out + (size_t)(gb + r) * 384;
            ((float2*)orow)[lane] = ((const float2*)(ufeat + (size_t)u * DD))[lane];
            ((float2*)orow)[64 + lane] = ((const float2*)(h1 + (size_t)u * DD))[lane];
        }
        __syncthreads();
        if (wave != 0) return;
        // phase 2: MFMA (wave 0 only)
        int um = users[gb + m];
        const float* selfp = h1 + (size_t)um * DD;
        bf16x8 sh[4], sl[4], nh[4], nl[4];
        #pragma unroll
        for (int kk = 0; kk < 4; ++kk) {
            int kb = kk * 32 + q * 8;
            make_afrag_hilo(selfp, kb, &sh[kk], &sl[kk]);
            make_afrag_hilo(sc + m * 132, kb, &nh[kk], &nl[kk]);
        }
        f32x4 acc[8];
        #pragma unroll
        for (int j = 0; j < 8; ++j) acc[j] = zero;
        #pragma unroll 2
        for (int j = 0; j < 8; ++j) {
            #pragma unroll
            for (int kk = 0; kk < 4; ++kk) {
                bf16x8 bs = bfrag(wf_u, (j * 4 + kk) * 64 + lane);
                acc[j] = mfma16(sh[kk], bs, acc[j]);
                acc[j] = mfma16(sl[kk], bs, acc[j]);
                bf16x8 bn = bfrag(wf_u, 2048 + (j * 4 + kk) * 64 + lane);
                acc[j] = mfma16(nh[kk], bn, acc[j]);
                acc[j] = mfma16(nl[kk], bn, acc[j]);
            }
        }
        float ss[4] = {0.f, 0.f, 0.f, 0.f};
        #pragma unroll
        for (int j = 0; j < 8; ++j) {
            float bj = bu1[j * 16 + m];
            #pragma unroll
            for (int r = 0; r < 4; ++r) {
                float x = acc[j][r] + bj;
                x = x > 0.f ? x : 0.2f * x;
                acc[j][r] = x;
                ss[r] += x * x;
            }
        }
        #pragma unroll
        for (int r = 0; r < 4; ++r) {
            float s = ss[r];
            s += __shfl_xor(s, 1, 64);
            s += __shfl_xor(s, 2, 64);
            s += __shfl_xor(s, 4, 64);
            s += __shfl_xor(s, 8, 64);
            ss[r] = 1.0f / fmaxf(sqrtf(s), 1e-12f);
        }
        #pragma unroll
        for (int j = 0; j < 8; ++j)
            #pragma unroll
            for (int r = 0; r < 4; ++r)
                out[(size_t)(gb + q * 4 + r) * 384 + 256 + j * 16 + m] = acc[j][r] * ss[r];
        return;
    }

    // ================= item side =================
    int tile = (blockIdx.x - 1024) * 4 + wave;  // 2048 tiles exact
    int gb = tile * 16;
    float* sc = scratch[wave];
    int rowm = gb + m;
    int idxm = (rowm < BB) ? pos[rowm] : neg[rowm - BB];
    const float* rowp = ifeat + (size_t)idxm * DD;
    bf16x8 ahi[4], alo[4];
    #pragma unroll
    for (int kk = 0; kk < 4; ++kk)
        make_afrag_hilo(rowp, kk * 32 + q * 8, &ahi[kk], &alo[kk]);
    f32x4 acc[8];
    #pragma unroll
    for (int j = 0; j < 8; ++j) acc[j] = zero;
    #pragma unroll 2
    for (int j = 0; j < 8; ++j) {
        #pragma unroll
        for (int kk = 0; kk < 4; ++kk) {
            bf16x8 b = bfrag(wf_i, (j * 4 + kk) * 64 + lane);
            acc[j] = mfma16(ahi[kk], b, acc[j]);
            acc[j] = mfma16(alo[kk], b, acc[j]);
        }
    }
    // epilogue 0 -> r1 in scratch
    float ss[4] = {0.f, 0.f, 0.f, 0.f};
    #pragma unroll
    for (int j = 0; j < 8; ++j) {
        float bj = bi0[j * 16 + m];
        #pragma unroll
        for (int r = 0; r < 4; ++r) {
            float x = acc[j][r] + bj;
            x = x > 0.f ? x : 0.2f * x;
            acc[j][r] = x;
            ss[r] += x * x;
        }
    }
    #pragma unroll
    for (int r = 0; r < 4; ++r) {
        float s = ss[r];
        s += __shfl_xor(s, 1, 64);
        s += __shfl_xor(s, 2, 64);
        s += __shfl_xor(s, 4, 64);
        s += __shfl_xor(s, 8, 64);
        ss[r] = 1.0f / fmaxf(sqrtf(s), 1e-12f);
    }
    #pragma unroll
    for (int j = 0; j < 8; ++j)
        #pragma unroll
        for (int r = 0; r < 4; ++r)
            sc[(q * 4 + r) * 132 + j * 16 + m] = acc[j][r] * ss[r];
    // copy r0 (raw gathered ifeat) and r1 (from scratch) to output
    for (int r = 0; r < 16; ++r) {
        int row = gb + r;
        int idx = (row < BB) ? pos[row] : neg[row - BB];
        float* orow = out + (size_t)(BB + row) * 384;  // pos b -> BB+b, neg b' -> 2BB+b' == BB+row
        ((float2*)orow)[lane] = ((const float2*)(ifeat + (size_t)idx * DD))[lane];
        float2 r1v;
        r1v.x = sc[r * 132 + 2 * lane];
        r1v.y = sc[r * 132 + 2 * lane + 1];
        ((float2*)orow)[64 + lane] = r1v;
    }
    // layer 1: A-frags from scratch
    bf16x8 chi[4], clo[4];
    #pragma unroll
    for (int kk = 0; kk < 4; ++kk)
        make_afrag_hilo(sc + m * 132, kk * 32 + q * 8, &chi[kk], &clo[kk]);
    #pragma unroll
    for (int j = 0; j < 8; ++j) acc[j] = zero;
    #pragma unroll 2
    for (int j = 0; j < 8; ++j) {
        #pragma unroll
        for (int kk = 0; kk < 4; ++kk) {
            bf16x8 b = bfrag(wf_i, 2048 + (j * 4 + kk) * 64 + lane);
            acc[j] = mfma16(chi[kk], b, acc[j]);
            acc[j] = mfma16(clo[kk], b, acc[j]);
        }
    }
    float ss1[4] = {0.f, 0.f, 0.f, 0.f};
    #pragma unroll
    for (int j = 0; j < 8; ++j) {
        float bj = bi1[j * 16 + m];
        #pragma unroll
        for (int r = 0; r < 4; ++r) {
            float x = acc[j][r] + bj;
            x = x > 0.f ? x : 0.2f * x;
            acc[j][r] = x;
            ss1[r] += x * x;
        }
    }
    #pragma unroll
    for (int r = 0; r < 4; ++r) {
        float s = ss1[r];
        s += __shfl_xor(s, 1, 64);
        s += __shfl_xor(s, 2, 64);
        s += __shfl_xor(s, 4, 64);
        s += __shfl_xor(s, 8, 64);
        ss1[r] = 1.0f / fmaxf(sqrtf(s), 1e-12f);
    }
    #pragma unroll
    for (int j = 0; j < 8; ++j)
        #pragma unroll
        for (int r = 0; r < 4; ++r)
            out[(size_t)(BB + gb + q * 4 + r) * 384 + 256 + j * 16 + m] = acc[j][r] * ss1[r];
}

extern "C" void kernel_launch(void* const* d_in, const int* in_sizes, int n_in,
                              void* d_out, int out_size, void* d_ws, size_t ws_size,
                              hipStream_t stream) {
    const int* src = (const int*)d_in[0];
    const int* dst = (const int*)d_in[1];
    const int* users = (const int*)d_in[2];
    const int* pos = (const int*)d_in[3];
    const int* neg = (const int*)d_in[4];
    const float* ufeat = (const float*)d_in[5];
    const float* ifeat = (const float*)d_in[6];
    const float* Ws0 = (const float*)d_in[7];
    const float* Wn0 = (const float*)d_in[8];
    const float* bu0 = (const float*)d_in[9];
    const float* Wi0 = (const float*)d_in[10];
    const float* bi0 = (const float*)d_in[11];
    const float* Ws1 = (const float*)d_in[12];
    const float* Wn1 = (const float*)d_in[13];
    const float* bu1 = (const float*)d_in[14];
    const float* Wi1 = (const float*)d_in[15];
    const float* bi1 = (const float*)d_in[16];
    float* out = (float*)d_out;

    char* ws = (char*)d_ws;
    int* deg = (int*)(ws + OFF_DEG);
    int* row_start = (int*)(ws + OFF_ROWSTART);
    int* bsum = (int*)(ws + OFF_BSUM);
    int* edge_src = (int*)(ws + OFF_EDGESRC);
    float* h1 = (float*)(ws + OFF_H1);
    u32x4* wfrag = (u32x4*)(ws + OFF_WFRAG);

    unsigned* ubf = (unsigned*)d_out;                                    // bf16 ufeat
    unsigned* hn = (unsigned*)((char*)d_out + (size_t)NU * DD * 2);      // bf16 neighbor mean
    int* hist = (int*)((char*)d_out + (size_t)NU * DD * 4);              // 12.8MB at +51.2MB
    const unsigned short* hn_us = (const unsigned short*)hn;

    mega_prep<<<HIST_BLKS + PACK_BLKS + CVT_BLKS, 256, 0, stream>>>(
        dst, hist, ufeat, ubf, Ws0, Wn0, Ws1, Wn1, Wi0, Wi1, wfrag);
    deg_reduce<<<(NU + 255) / 256, 256, 0, stream>>>(hist, deg);
    scan1_kernel<<<SCAN_NBLK, 256, 0, stream>>>(deg, bsum);
    scan2_kernel<<<1, 64, 0, stream>>>(bsum);
    scan3_kernel<<<SCAN_NBLK, 256, 0, stream>>>(deg, bsum, row_start);
    base_kernel<<<(NU + 255) / 256, 256, 0, stream>>>(row_start, hist);
    fill2<<<HIST_BLKS, 256, 0, stream>>>(src, dst, hist, edge_src);
    agg_kernel<<<(NU + 3) / 4, 256, 0, stream>>>(ubf, row_start, deg, edge_src, hn);
    user_mm_mfma<<<(USER_TILES + 3) / 4, 256, 0, stream>>>(ufeat, hn_us, wfrag, bu0, h1);
    tail_fuse<<<1024 + 512, 256, 0, stream>>>(ufeat, h1, users, row_start, deg, edge_src,
                                              ifeat, pos, neg, wfrag + 4096, wfrag + 8192,
                                              bu1, bi0, bi1, out);
}

// Round 6
// 440.108 us; speedup vs baseline: 1.3871x; 1.0299x over previous
//
#include <hip/hip_runtime.h>

#define NU 100000
#define NI 100000
#define NE 1600000
#define BB 16384
#define DD 128

static constexpr int SCAN_CHUNK = 2048;                       // 256 threads * 8
static constexpr int SCAN_NBLK  = (NU + SCAN_CHUNK - 1) / SCAN_CHUNK; // 49
static constexpr int USER_TILES = NU / 16;                    // 6250

static constexpr int NXCD   = 8;
static constexpr int DRANGE = NU / NXCD;                      // 12500 dsts per range
static constexpr int K_CH   = 32;                             // edge chunks
static constexpr int CHUNK4 = NE / 4 / K_CH;                  // 12500 int4 per chunk
static constexpr int HIST_BLKS = NXCD * K_CH;                 // 256
static constexpr int PACK_BLKS = 48;
static constexpr int CVT_UNIT  = 2048;                        // uint2 outputs per block
static constexpr int CVT_TOT   = NU * 32;                     // 3.2M uint2 (= NU*64 uints)
static constexpr int CVT_BLKS  = (CVT_TOT + CVT_UNIT - 1) / CVT_UNIT; // 1563

// ---------- workspace layout (bytes) ----------
static constexpr size_t OFF_DEG      = 0;          // int[NU]   400000
static constexpr size_t OFF_ROWSTART = 400128;     // int[NU]
static constexpr size_t OFF_BSUM     = 1200384;    // int[64]
static constexpr size_t OFF_EDGESRC  = 1200640;    // int[NE]   6400000
static constexpr size_t OFF_H1       = 7600640;    // float[NU*DD] 51200000
static constexpr size_t OFF_WFRAG    = 58800640;   // u32x4[12288] 196608 (pre-swizzled bf16 weights)

// d_out staging (dead before real outputs are written):
//   ubf  at d_out+0          : uint[NU*64]   25.6 MB (ufeat bf16 pairs; dead after agg)
//   hn   at d_out+25.6MB     : ushort[NU*128] 25.6 MB (neighbor mean; dead after user_mm)
//   hist at d_out+51.2MB     : int[8*32*12500] 12.8 MB (chunk histograms / cursor bases)

typedef __bf16 bf16x8 __attribute__((ext_vector_type(8)));
typedef float f32x4 __attribute__((ext_vector_type(4)));
typedef unsigned int u32x4 __attribute__((ext_vector_type(4)));

union frag_u {
    u32x4 u;
    bf16x8 b;
    unsigned short us[8];
};

// ---------- helpers ----------
__device__ __forceinline__ unsigned short f2bf(float f) {
    unsigned u = __float_as_uint(f);
    u = (u + 0x7fffu + ((u >> 16) & 1u)) >> 16;  // RNE
    return (unsigned short)u;
}

__device__ __forceinline__ unsigned pack_bf16_pair(float a, float b) {
    return (unsigned)f2bf(a) | ((unsigned)f2bf(b) << 16);
}

__device__ __forceinline__ float2 unpack_bf16_pair(unsigned u) {
    float2 r;
    r.x = __uint_as_float(u << 16);
    r.y = __uint_as_float(u & 0xffff0000u);
    return r;
}

__device__ __forceinline__ f32x4 mfma16(bf16x8 a, bf16x8 b, f32x4 c) {
    return __builtin_amdgcn_mfma_f32_16x16x32_bf16(a, b, c, 0, 0, 0);
}

__device__ __forceinline__ bf16x8 bfrag(const u32x4* __restrict__ wf, int idx) {
    frag_u f;
    f.u = wf[idx];
    return f.b;
}

// A-fragment (16x16x32 layout: lane holds A[m=lane&15][kb..kb+7]) as hi/lo bf16 split.
__device__ __forceinline__ void make_afrag_hilo(const float* rowp, int kb,
                                                bf16x8* hi, bf16x8* lo) {
    float4 v0 = *(const float4*)(rowp + kb);
    float4 v1 = *(const float4*)(rowp + kb + 4);
    float vv[8] = {v0.x, v0.y, v0.z, v0.w, v1.x, v1.y, v1.z, v1.w};
    frag_u h, l;
    #pragma unroll
    for (int e = 0; e < 8; ++e) {
        unsigned short hb = f2bf(vv[e]);
        h.us[e] = hb;
        float hf = __uint_as_float(((unsigned)hb) << 16);
        l.us[e] = f2bf(vv[e] - hf);
    }
    *hi = h.b;
    *lo = l.b;
}

// ---------- mega prep: LDS histograms + weight pack + ufeat cvt ----------
__global__ __launch_bounds__(256) void mega_prep(
    const int* __restrict__ dst, int* __restrict__ hist,
    const float* __restrict__ uf, unsigned* __restrict__ ubf,
    const float* __restrict__ Ws0, const float* __restrict__ Wn0,
    const float* __restrict__ Ws1, const float* __restrict__ Wn1,
    const float* __restrict__ Wi0, const float* __restrict__ Wi1,
    u32x4* __restrict__ wfrag) {
    __shared__ int h[DRANGE];  // 50 KB
    int t = threadIdx.x;
    if (blockIdx.x < HIST_BLKS) {
        int r = blockIdx.x & (NXCD - 1);
        int k = blockIdx.x >> 3;
        for (int j = t; j < DRANGE; j += 256) h[j] = 0;
        __syncthreads();
        int lo = r * DRANGE;
        const int4* d4 = (const int4*)dst + (size_t)k * CHUNK4;
        for (int i = t; i < CHUNK4; i += 256) {
            int4 d = d4[i];
            if ((unsigned)(d.x - lo) < (unsigned)DRANGE) atomicAdd(&h[d.x - lo], 1);
            if ((unsigned)(d.y - lo) < (unsigned)DRANGE) atomicAdd(&h[d.y - lo], 1);
            if ((unsigned)(d.z - lo) < (unsigned)DRANGE) atomicAdd(&h[d.z - lo], 1);
            if ((unsigned)(d.w - lo) < (unsigned)DRANGE) atomicAdd(&h[d.w - lo], 1);
        }
        __syncthreads();
        int* hb = hist + (size_t)(r * K_CH + k) * DRANGE;
        for (int j = t; j < DRANGE; j += 256) hb[j] = h[j];
    } else if (blockIdx.x < HIST_BLKS + PACK_BLKS) {
        int i = (blockIdx.x - HIST_BLKS) * 256 + t;  // 12288 exact
        const float* tab[6] = {Ws0, Wn0, Ws1, Wn1, Wi0, Wi1};
        int matg = i >> 11;
        int j = (i >> 8) & 7, kk = (i >> 6) & 3, ln = i & 63;
        const float* W = tab[matg];
        int n = j * 16 + (ln & 15);
        int kb = kk * 32 + (ln >> 4) * 8;
        unsigned short u[8];
        #pragma unroll
        for (int e = 0; e < 8; ++e) u[e] = f2bf(W[(size_t)(kb + e) * DD + n]);
        u32x4 w;
        w[0] = u[0] | ((unsigned)u[1] << 16);
        w[1] = u[2] | ((unsigned)u[3] << 16);
        w[2] = u[4] | ((unsigned)u[5] << 16);
        w[3] = u[6] | ((unsigned)u[7] << 16);
        wfrag[i] = w;
    } else {
        int bid2 = blockIdx.x - HIST_BLKS - PACK_BLKS;
        const float4* uf4 = (const float4*)uf;
        uint2* ub2 = (uint2*)ubf;
        #pragma unroll
        for (int it = 0; it < 8; ++it) {
            int idx = bid2 * CVT_UNIT + it * 256 + t;
            if (idx < CVT_TOT) {
                float4 v = uf4[idx];
                uint2 o;
                o.x = pack_bf16_pair(v.x, v.y);
                o.y = pack_bf16_pair(v.z, v.w);
                ub2[idx] = o;
            }
        }
    }
}

// ---------- deg[d] = sum_k hist[r][k][j] ----------
__global__ __launch_bounds__(256) void deg_reduce(const int* __restrict__ hist,
                                                  int* __restrict__ deg) {
    int d = blockIdx.x * 256 + threadIdx.x;
    if (d >= NU) return;
    int r = d / DRANGE, j = d - r * DRANGE;
    const int* hb = hist + (size_t)r * K_CH * DRANGE + j;
    int s = 0;
    #pragma unroll
    for (int k = 0; k < K_CH; ++k) s += hb[(size_t)k * DRANGE];
    deg[d] = s;
}

__global__ __launch_bounds__(256) void scan1_kernel(const int* __restrict__ deg,
                                                    int* __restrict__ bsum) {
    __shared__ int sh[256];
    int t = threadIdx.x;
    int base = blockIdx.x * SCAN_CHUNK + t * 8;
    int s = 0;
    #pragma unroll
    for (int j = 0; j < 8; ++j) {
        int idx = base + j;
        s += (idx < NU) ? deg[idx] : 0;
    }
    sh[t] = s;
    __syncthreads();
    for (int off = 128; off > 0; off >>= 1) {
        if (t < off) sh[t] += sh[t + off];
        __syncthreads();
    }
    if (t == 0) bsum[blockIdx.x] = sh[0];
}

__global__ void scan2_kernel(int* __restrict__ bsum) {
    if (threadIdx.x == 0) {
        int acc = 0;
        for (int i = 0; i < SCAN_NBLK; ++i) {
            int v = bsum[i];
            bsum[i] = acc;
            acc += v;
        }
    }
}

__global__ __launch_bounds__(256) void scan3_kernel(const int* __restrict__ deg,
                                                    const int* __restrict__ bsum,
                                                    int* __restrict__ row_start) {
    __shared__ int sh[256];
    int t = threadIdx.x;
    int base = blockIdx.x * SCAN_CHUNK + t * 8;
    int v[8];
    int s = 0;
    #pragma unroll
    for (int j = 0; j < 8; ++j) {
        int idx = base + j;
        v[j] = (idx < NU) ? deg[idx] : 0;
        s += v[j];
    }
    sh[t] = s;
    __syncthreads();
    for (int off = 1; off < 256; off <<= 1) {
        int val = sh[t];
        int add = (t >= off) ? sh[t - off] : 0;
        __syncthreads();
        sh[t] = val + add;
        __syncthreads();
    }
    int excl = sh[t] - s + bsum[blockIdx.x];
    #pragma unroll
    for (int j = 0; j < 8; ++j) {
        int idx = base + j;
        if (idx < NU) row_start[idx] = excl;
        excl += v[j];
    }
}

// ---------- hist -> per-(r,k) cursor bases (in place) ----------
__global__ __launch_bounds__(256) void base_kernel(const int* __restrict__ row_start,
                                                   int* __restrict__ hist) {
    int d = blockIdx.x * 256 + threadIdx.x;
    if (d >= NU) return;
    int r = d / DRANGE, j = d - r * DRANGE;
    int* hb = hist + (size_t)r * K_CH * DRANGE + j;
    int acc = row_start[d];
    #pragma unroll
    for (int k = 0; k < K_CH; ++k) {
        int c = hb[(size_t)k * DRANGE];
        hb[(size_t)k * DRANGE] = acc;
        acc += c;
    }
}

// ---------- CSR fill: LDS cursors only, zero global atomics ----------
__global__ __launch_bounds__(256) void fill2(const int* __restrict__ src,
                                             const int* __restrict__ dst,
                                             const int* __restrict__ base,
                                             int* __restrict__ edge_src) {
    __shared__ int cur[DRANGE];  // 50 KB
    int r = blockIdx.x & (NXCD - 1);
    int k = blockIdx.x >> 3;
    int t = threadIdx.x;
    const int* bb = base + (size_t)(r * K_CH + k) * DRANGE;
    for (int j = t; j < DRANGE; j += 256) cur[j] = bb[j];
    __syncthreads();
    int lo = r * DRANGE;
    const int4* d4 = (const int4*)dst + (size_t)k * CHUNK4;
    const int4* s4 = (const int4*)src + (size_t)k * CHUNK4;
    for (int i = t; i < CHUNK4; i += 256) {
        int4 d = d4[i];
        int4 s = s4[i];
        if ((unsigned)(d.x - lo) < (unsigned)DRANGE) edge_src[atomicAdd(&cur[d.x - lo], 1)] = s.x;
        if ((unsigned)(d.y - lo) < (unsigned)DRANGE) edge_src[atomicAdd(&cur[d.y - lo], 1)] = s.y;
        if ((unsigned)(d.z - lo) < (unsigned)DRANGE) edge_src[atomicAdd(&cur[d.z - lo], 1)] = s.z;
        if ((unsigned)(d.w - lo) < (unsigned)DRANGE) edge_src[atomicAdd(&cur[d.w - lo], 1)] = s.w;
    }
}

// ---------- layer-1 aggregation: 4 edge-slots x 16 lanelets per wave ----------
__global__ __launch_bounds__(256) void agg_kernel(const unsigned* __restrict__ ubf,
                                                  const int* __restrict__ row_start,
                                                  const int* __restrict__ deg,
                                                  const int* __restrict__ edge_src,
                                                  unsigned* __restrict__ hn) {
    int wid = blockIdx.x * 4 + (threadIdx.x >> 6);
    int lane = threadIdx.x & 63;
    if (wid >= NU) return;
    int st = row_start[wid];
    int dg = deg[wid];
    int lanelet = lane & 15;
    int eslot = lane >> 4;
    float acc[8] = {0.f, 0.f, 0.f, 0.f, 0.f, 0.f, 0.f, 0.f};
    const unsigned* colp = ubf + (lanelet << 2);
    for (int base = 0; base < dg; base += 64) {
        int n = min(dg - base, 64);
        int myidx = (lane < n) ? edge_src[st + base + lane] : 0;
        int e = 0;
        #pragma unroll 2
        for (; e + 4 <= n; e += 4) {
            int s = __shfl(myidx, e + eslot, 64);
            u32x4 v = *(const u32x4*)(colp + (size_t)s * 64);
            #pragma unroll
            for (int k = 0; k < 4; ++k) {
                float2 f = unpack_bf16_pair(v[k]);
                acc[2 * k] += f.x;
                acc[2 * k + 1] += f.y;
            }
        }
        int rem = n - e;
        int s = __shfl(myidx, min(e + eslot, 63), 64);
        if (eslot < rem) {
            u32x4 v = *(const u32x4*)(colp + (size_t)s * 64);
            #pragma unroll
            for (int k = 0; k < 4; ++k) {
                float2 f = unpack_bf16_pair(v[k]);
                acc[2 * k] += f.x;
                acc[2 * k + 1] += f.y;
            }
        }
    }
    #pragma unroll
    for (int k = 0; k < 8; ++k) {
        acc[k] += __shfl_xor(acc[k], 16, 64);
        acc[k] += __shfl_xor(acc[k], 32, 64);
    }
    float inv = 1.0f / fmaxf((float)dg, 1.0f);
    if (eslot == 0) {
        u32x4 o;
        o[0] = pack_bf16_pair(acc[0] * inv, acc[1] * inv);
        o[1] = pack_bf16_pair(acc[2] * inv, acc[3] * inv);
        o[2] = pack_bf16_pair(acc[4] * inv, acc[5] * inv);
        o[3] = pack_bf16_pair(acc[6] * inv, acc[7] * inv);
        *(u32x4*)(hn + (size_t)wid * 64 + (lanelet << 2)) = o;
    }
}

// ---------- user layer 1 (all rows), MFMA ----------
__global__ __launch_bounds__(256) void user_mm_mfma(
    const float* __restrict__ hself, const unsigned short* __restrict__ hn,
    const u32x4* __restrict__ wf, const float* __restrict__ bias,
    float* __restrict__ out) {
    int t = threadIdx.x;
    int lane = t & 63;
    int tile = blockIdx.x * 4 + (t >> 6);
    if (tile >= USER_TILES) return;
    int gbase = tile * 16;
    int m = lane & 15, q = lane >> 4;
    const float* selfp = hself + (size_t)(gbase + m) * DD;
    const unsigned short* neighp = hn + (size_t)(gbase + m) * DD;
    bf16x8 as_hi[4], as_lo[4], an[4];
    #pragma unroll
    for (int kk = 0; kk < 4; ++kk) {
        int kb = kk * 32 + q * 8;
        make_afrag_hilo(selfp, kb, &as_hi[kk], &as_lo[kk]);
        frag_u f;
        f.u = *(const u32x4*)(neighp + kb);
        an[kk] = f.b;
    }
    f32x4 acc[8];
    f32x4 zero = {0.f, 0.f, 0.f, 0.f};
    #pragma unroll
    for (int j = 0; j < 8; ++j) acc[j] = zero;
    #pragma unroll 2
    for (int j = 0; j < 8; ++j) {
        #pragma unroll
        for (int kk = 0; kk < 4; ++kk) {
            bf16x8 bs = bfrag(wf, (j * 4 + kk) * 64 + lane);
            acc[j] = mfma16(as_hi[kk], bs, acc[j]);
            acc[j] = mfma16(as_lo[kk], bs, acc[j]);
            bf16x8 bn = bfrag(wf, 2048 + (j * 4 + kk) * 64 + lane);
            acc[j] = mfma16(an[kk], bn, acc[j]);
        }
    }
    float ss[4] = {0.f, 0.f, 0.f, 0.f};
    #pragma unroll
    for (int j = 0; j < 8; ++j) {
        float bj = bias[j * 16 + m];
        #pragma unroll
        for (int r = 0; r < 4; ++r) {
            float x = acc[j][r] + bj;
            x = x > 0.f ? x : 0.2f * x;
            acc[j][r] = x;
            ss[r] += x * x;
        }
    }
    #pragma unroll
    for (int r = 0; r < 4; ++r) {
        float s = ss[r];
        s += __shfl_xor(s, 1, 64);
        s += __shfl_xor(s, 2, 64);
        s += __shfl_xor(s, 4, 64);
        s += __shfl_xor(s, 8, 64);
        ss[r] = 1.0f / fmaxf(sqrtf(s), 1e-12f);
    }
    #pragma unroll
    for (int j = 0; j < 8; ++j)
        #pragma unroll
        for (int r = 0; r < 4; ++r)
            out[(size_t)(gbase + q * 4 + r) * DD + j * 16 + m] = acc[j][r] * ss[r];
}

// ---------- fused tail: user_l2 (blocks 0..1023) + item (blocks 1024..3071) ----
// One 16-row tile per BLOCK; the 8 j-columns split 2 per wave so all 4 waves run
// the MFMA phase. Row L2-norm crosses waves via ssp[] in LDS. LDS = 8.7 KB ->
// thread-capped 8 blocks/CU (was LDS-capped at 4 with 3/4 waves idle).
__global__ __launch_bounds__(256) void tail_fuse(
    const float* __restrict__ ufeat, const float* __restrict__ h1,
    const int* __restrict__ users, const int* __restrict__ row_start,
    const int* __restrict__ deg, const int* __restrict__ edge_src,
    const float* __restrict__ ifeat, const int* __restrict__ pos,
    const int* __restrict__ neg, const u32x4* __restrict__ wf_u,
    const u32x4* __restrict__ wf_i, const float* __restrict__ bu1,
    const float* __restrict__ bi0, const float* __restrict__ bi1,
    float* __restrict__ out) {
    __shared__ float sc[16 * 132];   // 8448 B tile scratch
    __shared__ float ssp[16 * 4];    // per-row per-wave partial sum-of-squares
    int t = threadIdx.x;
    int lane = t & 63, wave = t >> 6;
    int m = lane & 15, q = lane >> 4;
    f32x4 zero = {0.f, 0.f, 0.f, 0.f};

    if (blockIdx.x < 1024) {
        // ================= user layer 2 =================
        int gb = blockIdx.x * 16;
        int L = lane & 31;      // 16B lanelet of the row
        int eslot = lane >> 5;  // 2 concurrent edges
        const float* hl = h1 + 4 * L;
        // phase 1: wave w aggregates rows 4w..4w+3 of h1 into sc + copies cols 0..255.
        // Edge indices prefetched coalesced, redistributed by shfl (no per-iter
        // index load on the dependent chain).
        #pragma unroll
        for (int rr = 0; rr < 4; ++rr) {
            int r = wave * 4 + rr;
            int u = users[gb + r];
            int st = row_start[u], dg = deg[u];
            float ax = 0.f, ay = 0.f, az = 0.f, aw = 0.f;
            for (int base = 0; base < dg; base += 64) {
                int n = min(dg - base, 64);
                int myidx = (lane < n) ? edge_src[st + base + lane] : 0;
                int e = 0;
                #pragma unroll 4
                for (; e + 2 <= n; e += 2) {
                    int s = __shfl(myidx, e + eslot, 64);
                    float4 v = *(const float4*)(hl + (size_t)s * DD);
                    ax += v.x; ay += v.y; az += v.z; aw += v.w;
                }
                if (e < n) {
                    int s = __shfl(myidx, e, 64);
                    if (eslot == 0) {
                        float4 v = *(const float4*)(hl + (size_t)s * DD);
                        ax += v.x; ay += v.y; az += v.z; aw += v.w;
                    }
                }
            }
            ax += __shfl_xor(ax, 32, 64);
            ay += __shfl_xor(ay, 32, 64);
            az += __shfl_xor(az, 32, 64);
            aw += __shfl_xor(aw, 32, 64);
            float inv = 1.0f / fmaxf((float)dg, 1.0f);
            if (eslot == 0) {
                float4 o = {ax * inv, ay * inv, az * inv, aw * inv};
                *(float4*)(sc + r * 132 + 4 * L) = o;
            }
            float* orow = out + (size_t)(gb + r) * 384;
            ((float2*)orow)[lane] = ((const float2*)(ufeat + (size_t)u * DD))[lane];
            ((float2*)orow)[64 + lane] = ((const float2*)(h1 + (size_t)u * DD))[lane];
        }
        __syncthreads();
        // phase 2: all 4 waves; wave w computes j = 2w, 2w+1
        int j0 = wave * 2;
        int um = users[gb + m];
        const float* selfp = h1 + (size_t)um * DD;
        bf16x8 sh[4], sl[4], nh[4], nl[4];
        #pragma unroll
        for (int kk = 0; kk < 4; ++kk) {
            int kb = kk * 32 + q * 8;
            make_afrag_hilo(selfp, kb, &sh[kk], &sl[kk]);
            make_afrag_hilo(sc + m * 132, kb, &nh[kk], &nl[kk]);
        }
        f32x4 a0 = zero, a1 = zero;
        #pragma unroll
        for (int kk = 0; kk < 4; ++kk) {
            bf16x8 b0 = bfrag(wf_u, (j0 * 4 + kk) * 64 + lane);
            a0 = mfma16(sh[kk], b0, a0);
            a0 = mfma16(sl[kk], b0, a0);
            bf16x8 n0 = bfrag(wf_u, 2048 + (j0 * 4 + kk) * 64 + lane);
            a0 = mfma16(nh[kk], n0, a0);
            a0 = mfma16(nl[kk], n0, a0);
            bf16x8 b1 = bfrag(wf_u, ((j0 + 1) * 4 + kk) * 64 + lane);
            a1 = mfma16(sh[kk], b1, a1);
            a1 = mfma16(sl[kk], b1, a1);
            bf16x8 n1 = bfrag(wf_u, 2048 + ((j0 + 1) * 4 + kk) * 64 + lane);
            a1 = mfma16(nh[kk], n1, a1);
            a1 = mfma16(nl[kk], n1, a1);
        }
        float bj0 = bu1[j0 * 16 + m], bj1 = bu1[(j0 + 1) * 16 + m];
        float ss[4];
        #pragma unroll
        for (int r = 0; r < 4; ++r) {
            float x0 = a0[r] + bj0; x0 = x0 > 0.f ? x0 : 0.2f * x0; a0[r] = x0;
            float x1 = a1[r] + bj1; x1 = x1 > 0.f ? x1 : 0.2f * x1; a1[r] = x1;
            float s = x0 * x0 + x1 * x1;
            s += __shfl_xor(s, 1, 64);
            s += __shfl_xor(s, 2, 64);
            s += __shfl_xor(s, 4, 64);
            s += __shfl_xor(s, 8, 64);
            ss[r] = s;
        }
        if (m == 0) {
            #pragma unroll
            for (int r = 0; r < 4; ++r) ssp[(q * 4 + r) * 4 + wave] = ss[r];
        }
        __syncthreads();
        #pragma unroll
        for (int r = 0; r < 4; ++r) {
            int row = q * 4 + r;
            float tot = ssp[row * 4] + ssp[row * 4 + 1] + ssp[row * 4 + 2] + ssp[row * 4 + 3];
            float inv = 1.0f / fmaxf(sqrtf(tot), 1e-12f);
            out[(size_t)(gb + row) * 384 + 256 + j0 * 16 + m] = a0[r] * inv;
            out[(size_t)(gb + row) * 384 + 256 + (j0 + 1) * 16 + m] = a1[r] * inv;
        }
        return;
    }

    // ================= item side: one tile per block, j split across waves =====
    int tile = blockIdx.x - 1024;  // 2048 tiles
    int gb = tile * 16;
    int j0 = wave * 2;
    int rowm = gb + m;
    int idxm = (rowm < BB) ? pos[rowm] : neg[rowm - BB];
    const float* rowp = ifeat + (size_t)idxm * DD;
    bf16x8 ahi[4], alo[4];
    #pragma unroll
    for (int kk = 0; kk < 4; ++kk)
        make_afrag_hilo(rowp, kk * 32 + q * 8, &ahi[kk], &alo[kk]);
    f32x4 a0 = zero, a1 = zero;
    #pragma unroll
    for (int kk = 0; kk < 4; ++kk) {
        bf16x8 b0 = bfrag(wf_i, (j0 * 4 + kk) * 64 + lane);
        a0 = mfma16(ahi[kk], b0, a0);
        a0 = mfma16(alo[kk], b0, a0);
        bf16x8 b1 = bfrag(wf_i, ((j0 + 1) * 4 + kk) * 64 + lane);
        a1 = mfma16(ahi[kk], b1, a1);
        a1 = mfma16(alo[kk], b1, a1);
    }
    // epilogue 0: cross-wave norm, write r1 to scratch
    {
        float bj0 = bi0[j0 * 16 + m], bj1 = bi0[(j0 + 1) * 16 + m];
        float ss[4];
        #pragma unroll
        for (int r = 0; r < 4; ++r) {
            float x0 = a0[r] + bj0; x0 = x0 > 0.f ? x0 : 0.2f * x0; a0[r] = x0;
            float x1 = a1[r] + bj1; x1 = x1 > 0.f ? x1 : 0.2f * x1; a1[r] = x1;
            float s = x0 * x0 + x1 * x1;
            s += __shfl_xor(s, 1, 64);
            s += __shfl_xor(s, 2, 64);
            s += __shfl_xor(s, 4, 64);
            s += __shfl_xor(s, 8, 64);
            ss[r] = s;
        }
        if (m == 0) {
            #pragma unroll
            for (int r = 0; r < 4; ++r) ssp[(q * 4 + r) * 4 + wave] = ss[r];
        }
        __syncthreads();
        #pragma unroll
        for (int r = 0; r < 4; ++r) {
            int row = q * 4 + r;
            float tot = ssp[row * 4] + ssp[row * 4 + 1] + ssp[row * 4 + 2] + ssp[row * 4 + 3];
            float inv = 1.0f / fmaxf(sqrtf(tot), 1e-12f);
            sc[row * 132 + j0 * 16 + m] = a0[r] * inv;
            sc[row * 132 + (j0 + 1) * 16 + m] = a1[r] * inv;
        }
        __syncthreads();
    }
    // copy r0 (raw gathered ifeat) and r1 (from scratch): rows split across waves
    #pragma unroll
    for (int rr = 0; rr < 4; ++rr) {
        int r = wave * 4 + rr;
        int row = gb + r;
        int idx = (row < BB) ? pos[row] : neg[row - BB];
        float* orow = out + (size_t)(BB + row) * 384;
        ((float2*)orow)[lane] = ((const float2*)(ifeat + (size_t)idx * DD))[lane];
        float2 r1v;
        r1v.x = sc[r * 132 + 2 * lane];
        r1v.y = sc[r * 132 + 2 * lane + 1];
        ((float2*)orow)[64 + lane] = r1v;
    }
    // layer 1: A-frags from scratch
    bf16x8 chi[4], clo[4];
    #pragma unroll
    for (int kk = 0; kk < 4; ++kk)
        make_afrag_hilo(sc + m * 132, kk * 32 + q * 8, &chi[kk], &clo[kk]);
    a0 = zero; a1 = zero;
    #pragma unroll
    for (int kk = 0; kk < 4; ++kk) {
        bf16x8 b0 = bfrag(wf_i, 2048 + (j0 * 4 + kk) * 64 + lane);
        a0 = mfma16(chi[kk], b0, a0);
        a0 = mfma16(clo[kk], b0, a0);
        bf16x8 b1 = bfrag(wf_i, 2048 + ((j0 + 1) * 4 + kk) * 64 + lane);
        a1 = mfma16(chi[kk], b1, a1);
        a1 = mfma16(clo[kk], b1, a1);
    }
    {
        float bj0 = bi1[j0 * 16 + m], bj1 = bi1[(j0 + 1) * 16 + m];
        float ss[4];
        #pragma unroll
        for (int r = 0; r < 4; ++r) {
            float x0 = a0[r] + bj0; x0 = x0 > 0.f ? x0 : 0.2f * x0; a0[r] = x0;
            float x1 = a1[r] + bj1; x1 = x1 > 0.f ? x1 : 0.2f * x1; a1[r] = x1;
            float s = x0 * x0 + x1 * x1;
            s += __shfl_xor(s, 1, 64);
            s += __shfl_xor(s, 2, 64);
            s += __shfl_xor(s, 4, 64);
            s += __shfl_xor(s, 8, 64);
            ss[r] = s;
        }
        __syncthreads();  // ensure prior ssp reads done before rewrite
        if (m == 0) {
            #pragma unroll
            for (int r = 0; r < 4; ++r) ssp[(q * 4 + r) * 4 + wave] = ss[r];
        }
        __syncthreads();
        #pragma unroll
        for (int r = 0; r < 4; ++r) {
            int row = q * 4 + r;
            float tot = ssp[row * 4] + ssp[row * 4 + 1] + ssp[row * 4 + 2] + ssp[row * 4 + 3];
            float inv = 1.0f / fmaxf(sqrtf(tot), 1e-12f);
            out[(size_t)(BB + gb + row) * 384 + 256 + j0 * 16 + m] = a0[r] * inv;
            out[(size_t)(BB + gb + row) * 384 + 256 + (j0 + 1) * 16 + m] = a1[r] * inv;
        }
    }
}

extern "C" void kernel_launch(void* const* d_in, const int* in_sizes, int n_in,
                              void* d_out, int out_size, void* d_ws, size_t ws_size,
                              hipStream_t stream) {
    const int* src = (const int*)d_in[0];
    const int* dst = (const int*)d_in[1];
    const int* users = (const int*)d_in[2];
    const int* pos = (const int*)d_in[3];
    const int* neg = (const int*)d_in[4];
    const float* ufeat = (const float*)d_in[5];
    const float* ifeat = (const float*)d_in[6];
    const float* Ws0 = (const float*)d_in[7];
    const float* Wn0 = (const float*)d_in[8];
    const float* bu0 = (const float*)d_in[9];
    const float* Wi0 = (const float*)d_in[10];
    const float* bi0 = (const float*)d_in[11];
    const float* Ws1 = (const float*)d_in[12];
    const float* Wn1 = (const float*)d_in[13];
    const float* bu1 = (const float*)d_in[14];
    const float* Wi1 = (const float*)d_in[15];
    const float* bi1 = (const float*)d_in[16];
    float* out = (float*)d_out;

    char* ws = (char*)d_ws;
    int* deg = (int*)(ws + OFF_DEG);
    int* row_start = (int*)(ws + OFF_ROWSTART);
    int* bsum = (int*)(ws + OFF_BSUM);
    int* edge_src = (int*)(ws + OFF_EDGESRC);
    float* h1 = (float*)(ws + OFF_H1);
    u32x4* wfrag = (u32x4*)(ws + OFF_WFRAG);

    unsigned* ubf = (unsigned*)d_out;                                    // bf16 ufeat
    unsigned* hn = (unsigned*)((char*)d_out + (size_t)NU * DD * 2);      // bf16 neighbor mean
    int* hist = (int*)((char*)d_out + (size_t)NU * DD * 4);              // 12.8MB at +51.2MB
    const unsigned short* hn_us = (const unsigned short*)hn;

    mega_prep<<<HIST_BLKS + PACK_BLKS + CVT_BLKS, 256, 0, stream>>>(
        dst, hist, ufeat, ubf, Ws0, Wn0, Ws1, Wn1, Wi0, Wi1, wfrag);
    deg_reduce<<<(NU + 255) / 256, 256, 0, stream>>>(hist, deg);
    scan1_kernel<<<SCAN_NBLK, 256, 0, stream>>>(deg, bsum);
    scan2_kernel<<<1, 64, 0, stream>>>(bsum);
    scan3_kernel<<<SCAN_NBLK, 256, 0, stream>>>(deg, bsum, row_start);
    base_kernel<<<(NU + 255) / 256, 256, 0, stream>>>(row_start, hist);
    fill2<<<HIST_BLKS, 256, 0, stream>>>(src, dst, hist, edge_src);
    agg_kernel<<<(NU + 3) / 4, 256, 0, stream>>>(ubf, row_start, deg, edge_src, hn);
    user_mm_mfma<<<(USER_TILES + 3) / 4, 256, 0, stream>>>(ufeat, hn_us, wfrag, bu0, h1);
    tail_fuse<<<1024 + 2048, 256, 0, stream>>>(ufeat, h1, users, row_start, deg, edge_src,
                                               ifeat, pos, neg, wfrag + 4096, wfrag + 8192,
                                               bu1, bi0, bi1, out);
}